// Round 17
// baseline (346.203 us; speedup 1.0000x reference)
//
#include <hip/hip_runtime.h>
#include <math.h>

#define N 4096
#define D 128
#define H 512
#define INV_T 5.0f
#define KSPLIT 4

typedef short bf16x8 __attribute__((ext_vector_type(8)));
typedef float f32x4 __attribute__((ext_vector_type(4)));
typedef unsigned short u16x8 __attribute__((ext_vector_type(8)));
typedef unsigned short u16;
typedef _Float16 f16;
typedef _Float16 f16x4 __attribute__((ext_vector_type(4)));

#define MFMA(a, b, c) __builtin_amdgcn_mfma_f32_16x16x32_bf16((a), (b), (c), 0, 0, 0)

__device__ __forceinline__ float bf2f(u16 h)
{
    return __uint_as_float(((unsigned)h) << 16);
}

// Round-to-nearest bf16 (unbiased) — for operands whose hi is used ALONE.
__device__ __forceinline__ u16 rtn_bf16(float v)
{
    unsigned u = __float_as_uint(v);
    return (u16)((u + 0x7FFFu + ((u >> 16) & 1u)) >> 16);
}

// RTN split (hi usable alone; lo compensates). Cold paths + last gen layer.
__device__ __forceinline__ void split1(float v, u16& h, u16& l)
{
    u16 hh = rtn_bf16(v);
    float r = v - bf2f(hh);
    h = hh;
    l = rtn_bf16(r);
}

// Cheap truncation split (3 ops); hi+lo pair accuracy identical.
__device__ __forceinline__ void split1_trunc(float v, u16& h, u16& l)
{
    unsigned bv = __float_as_uint(v);
    unsigned hb = bv & 0xFFFF0000u;
    float r = v - __uint_as_float(hb);
    h = (u16)(hb >> 16);
    l = (u16)(__float_as_uint(r) >> 16);
}

// ---------------------------------------------------------------------------
// One-shot splitter for 5 flat fp32 arrays -> bf16 hi/lo (RTN, cold) and,
// on the y==5 plane, workspace init (acc/sp/sn/nx/ny).
// ---------------------------------------------------------------------------
struct SplitDesc { const float* src; u16* h; u16* l; int n; };
struct SplitArgs { SplitDesc d[5]; };

__global__ __launch_bounds__(256) void split_multi(SplitArgs args,
    double* acc, float* sp, float* sn, float* nx, float* ny)
{
    if (blockIdx.y == 5) {
        int idx = blockIdx.x * 256 + threadIdx.x;
        if (idx == 0) *acc = 0.0;
        if (idx < N) { sp[idx] = 0.f; sn[idx] = 0.f; nx[idx] = 0.f; ny[idx] = 0.f; }
        return;
    }
    SplitDesc de = args.d[blockIdx.y];
    int idx = (blockIdx.x * 256 + threadIdx.x) * 4;
    if (idx >= de.n) return;
    float4 v = *(const float4*)(de.src + idx);
    ushort4 hv, lv;
    split1(v.x, hv.x, lv.x); split1(v.y, hv.y, lv.y);
    split1(v.z, hv.z, lv.z); split1(v.w, hv.w, lv.w);
    *(ushort4*)(de.h + idx) = hv;
    *(ushort4*)(de.l + idx) = lv;
}

// ---------------------------------------------------------------------------
// Transpose + RTN-bf16 + fused row-norm partials (atomicAdd into nx/ny).
// ---------------------------------------------------------------------------
__global__ __launch_bounds__(256) void transpose_rtn(
    const float* __restrict__ X, const float* __restrict__ Y,
    u16* __restrict__ Xth, u16* __restrict__ Yth,
    float* __restrict__ nx, float* __restrict__ ny)
{
    const float* src = blockIdx.z ? Y : X;
    u16* th = blockIdx.z ? Yth : Xth;
    float* nrm = blockIdx.z ? ny : nx;
    __shared__ float tile[32][33];
    const int t = threadIdx.x;
    const int r0 = blockIdx.x * 32, c0 = blockIdx.y * 32;
    {
        int rit = t >> 3, coff = (t & 7) * 4;
        float4 v = *(const float4*)(src + (size_t)(r0 + rit) * D + c0 + coff);
        tile[rit][coff + 0] = v.x; tile[rit][coff + 1] = v.y;
        tile[rit][coff + 2] = v.z; tile[rit][coff + 3] = v.w;
        float sq = v.x * v.x + v.y * v.y + v.z * v.z + v.w * v.w;
        sq += __shfl_xor(sq, 1);
        sq += __shfl_xor(sq, 2);
        sq += __shfl_xor(sq, 4);
        if ((t & 7) == 0) atomicAdd(&nrm[r0 + rit], sq);
    }
    __syncthreads();
    {
        int cit = t >> 3, roff = (t & 7) * 4;
        ushort4 hv;
        hv.x = rtn_bf16(tile[roff + 0][cit]);
        hv.y = rtn_bf16(tile[roff + 1][cit]);
        hv.z = rtn_bf16(tile[roff + 2][cit]);
        hv.w = rtn_bf16(tile[roff + 3][cit]);
        *(ushort4*)(th + (size_t)(c0 + cit) * N + r0 + roff) = hv;
    }
}

// ---------------------------------------------------------------------------
// Generator GEMM: A = activations hi/lo bf16 pair, B = weights single RTN
// bf16. Tile 64x64, BK=32, 128 threads. rtn_out=1 on the last layer only.
// ---------------------------------------------------------------------------
__global__ __launch_bounds__(128) void gen_gemm(
    const u16* __restrict__ Ah, const u16* __restrict__ Al,
    const u16* __restrict__ Bh,
    const float* __restrict__ bias,
    float* __restrict__ C, u16* __restrict__ Ch, u16* __restrict__ Cl,
    int M, int Nn, int K, int resid, int rtn_out)
{
    __shared__ u16 AhS[64][40], AlS[64][40];
    __shared__ u16 BhS[64][40];
    const int t = threadIdx.x;
    const int w = t >> 6, lane = t & 63;
    const int quad = lane >> 4, l16 = lane & 15;
    const int bm = blockIdx.y * 64, bn = blockIdx.x * 64;
    f32x4 acc[2][4] = {};

    for (int k0 = 0; k0 < K; k0 += 32) {
        __syncthreads();
        #pragma unroll
        for (int p = 0; p < 2; ++p) {
            int slot = t + p * 128;
            int row = slot >> 2, koff = (slot & 3) << 3;
            size_t ga = (size_t)(bm + row) * K + k0 + koff;
            size_t gb = (size_t)(bn + row) * K + k0 + koff;
            *(u16x8*)&AhS[row][koff] = *(const u16x8*)(Ah + ga);
            *(u16x8*)&AlS[row][koff] = *(const u16x8*)(Al + ga);
            *(u16x8*)&BhS[row][koff] = *(const u16x8*)(Bh + gb);
        }
        __syncthreads();
        bf16x8 af[2], alf[2], bhf[4];
        #pragma unroll
        for (int mi = 0; mi < 2; ++mi) {
            int r = w * 32 + mi * 16 + l16;
            af[mi]  = *(const bf16x8*)&AhS[r][quad * 8];
            alf[mi] = *(const bf16x8*)&AlS[r][quad * 8];
        }
        #pragma unroll
        for (int ni = 0; ni < 4; ++ni)
            bhf[ni] = *(const bf16x8*)&BhS[ni * 16 + l16][quad * 8];
        #pragma unroll
        for (int mi = 0; mi < 2; ++mi)
            #pragma unroll
            for (int ni = 0; ni < 4; ++ni) {
                acc[mi][ni] = MFMA(af[mi], bhf[ni], acc[mi][ni]);
                acc[mi][ni] = MFMA(alf[mi], bhf[ni], acc[mi][ni]);
            }
    }
    #pragma unroll
    for (int mi = 0; mi < 2; ++mi)
        #pragma unroll
        for (int ni = 0; ni < 4; ++ni)
            #pragma unroll
            for (int r = 0; r < 4; ++r) {
                int gm = bm + w * 32 + mi * 16 + quad * 4 + r;
                int gn = bn + ni * 16 + l16;
                float v = acc[mi][ni][r] + bias[gn];
                if (resid) {
                    size_t o2 = (size_t)gm * K + gn;
                    float prev = bf2f(Ah[o2]) + bf2f(Al[o2]);
                    v = prev + fmaxf(v, 0.0f);
                }
                size_t o = (size_t)gm * Nn + gn;
                if (C) C[o] = v;
                u16 hh, ll;
                if (rtn_out) split1(v, hh, ll);
                else         split1_trunc(v, hh, ll);
                Ch[o] = hh; Cl[o] = ll;
            }
}

// ---------------------------------------------------------------------------
// Distance via SINGLE RTN-bf16 MFMA, fused stats, pos+neg merged. A fp16.
// B-operand COLUMN PERMUTATION: Y row j sits in LDS row s=(j&3)*16+(j>>2)
// (per 64-half), so fragment slot (ni,l16) holds j = l16*4+ni -> each lane's
// 4 outputs per (mi,r) are j-contiguous: ONE f16x4 store (was 4 scalar) and
// ny is one float4 load (was 4 scalar). XOR k-rotation per LDS row keeps
// staging writes & fragment reads conflict-free.
// ---------------------------------------------------------------------------
__global__ __launch_bounds__(256) void dist_fused(
    const u16* __restrict__ Xh, const u16* __restrict__ Yh,
    const float* __restrict__ nx, const float* __restrict__ ny,
    f16* __restrict__ Apos, f16* __restrict__ Aneg,
    float* __restrict__ prm_p, float* __restrict__ prs_p,
    float* __restrict__ pcm_p, float* __restrict__ pcs_p,
    float* __restrict__ prm_n, float* __restrict__ prs_n)
{
    const int mat = blockIdx.z;                // 0: X vs Y ; 1: X vs X
    const u16* Bhp = mat ? Xh : Yh;
    const float* nb = mat ? nx : ny;
    f16* Out = mat ? Aneg : Apos;
    float* prm = mat ? prm_n : prm_p;
    float* prs = mat ? prs_n : prs_p;

    __shared__ u16 XhS[128][40], YhS[128][40];
    const int t = threadIdx.x;
    const int w = t >> 6, lane = t & 63;
    const int quad = lane >> 4, l16 = lane & 15;
    const int wm = w & 1, wn = w >> 1;
    const int bm = blockIdx.y * 128, bn = blockIdx.x * 128;
    f32x4 acc[4][4] = {};

    for (int k0 = 0; k0 < D; k0 += 32) {
        __syncthreads();
        #pragma unroll
        for (int p = 0; p < 2; ++p) {
            int slot = t + p * 256;            // 512 slots = 128 rows x 4 octets
            int row = slot >> 2, koff = (slot & 3) << 3;
            *(u16x8*)&XhS[row][koff] =
                *(const u16x8*)(Xh + (size_t)(bm + row) * D + k0 + koff);
            int pr = ((row & 3) << 4) | ((row & 63) >> 2) | (row & 64);
            int kf = koff ^ (((pr >> 4) & 3) << 3);
            *(u16x8*)&YhS[pr][kf] =
                *(const u16x8*)(Bhp + (size_t)(bn + row) * D + k0 + koff);
        }
        __syncthreads();
        bf16x8 af[4], bhf[4];
        #pragma unroll
        for (int mi = 0; mi < 4; ++mi)
            af[mi] = *(const bf16x8*)&XhS[wm * 64 + mi * 16 + l16][quad * 8];
        #pragma unroll
        for (int ni = 0; ni < 4; ++ni)
            bhf[ni] = *(const bf16x8*)
                &YhS[wn * 64 + ni * 16 + l16][(quad * 8) ^ ((ni & 3) << 3)];
        #pragma unroll
        for (int mi = 0; mi < 4; ++mi)
            #pragma unroll
            for (int ni = 0; ni < 4; ++ni)
                acc[mi][ni] = MFMA(af[mi], bhf[ni], acc[mi][ni]);
    }
    // lane's 4 j's are contiguous: jb..jb+3
    const int jb = bn + wn * 64 + (l16 << 2);
    const float4 nyv = *(const float4*)(nb + jb);
    const float nyl[4] = {nyv.x, nyv.y, nyv.z, nyv.w};
    // --- transform in place + vector store ---
    #pragma unroll
    for (int mi = 0; mi < 4; ++mi)
        #pragma unroll
        for (int r = 0; r < 4; ++r) {
            int gm = bm + wm * 64 + mi * 16 + quad * 4 + r;
            float nxm = nx[gm];
            f16x4 ov;
            #pragma unroll
            for (int ni = 0; ni < 4; ++ni) {
                float d2 = nxm + nyl[ni] - 2.0f * acc[mi][ni][r];
                float a = -sqrtf(fmaxf(d2, 0.0f)) * INV_T;
                if (mat && gm == jb + ni) a = -5.0e6f;
                acc[mi][ni][r] = a;
                ov[ni] = (f16)a;
            }
            *(f16x4*)(Out + (size_t)gm * N + jb) = ov;
        }
    // --- row partials: per (mi,r), reduce over ni (in-lane) + l16 (shfl) ---
    const int ct = blockIdx.x * 2 + wn;
    #pragma unroll
    for (int mi = 0; mi < 4; ++mi)
        #pragma unroll
        for (int r = 0; r < 4; ++r) {
            float m = fmaxf(fmaxf(acc[mi][0][r], acc[mi][1][r]),
                            fmaxf(acc[mi][2][r], acc[mi][3][r]));
            m = fmaxf(m, __shfl_xor(m, 1));
            m = fmaxf(m, __shfl_xor(m, 2));
            m = fmaxf(m, __shfl_xor(m, 4));
            m = fmaxf(m, __shfl_xor(m, 8));
            float s = __expf(acc[mi][0][r] - m) + __expf(acc[mi][1][r] - m)
                    + __expf(acc[mi][2][r] - m) + __expf(acc[mi][3][r] - m);
            s += __shfl_xor(s, 1); s += __shfl_xor(s, 2);
            s += __shfl_xor(s, 4); s += __shfl_xor(s, 8);
            if (l16 == 0) {
                int grow = bm + wm * 64 + mi * 16 + quad * 4 + r;
                prm[(size_t)ct * N + grow] = m;
                prs[(size_t)ct * N + grow] = s;
            }
        }
    // --- col partials (pos only): per ni, in-lane over (mi,r) + quad shfl ---
    if (mat == 0) {
        const int rt = blockIdx.y * 2 + wm;
        #pragma unroll
        for (int ni = 0; ni < 4; ++ni) {
            float m = -3.0e38f;
            #pragma unroll
            for (int mi = 0; mi < 4; ++mi)
                #pragma unroll
                for (int r = 0; r < 4; ++r)
                    m = fmaxf(m, acc[mi][ni][r]);
            m = fmaxf(m, __shfl_xor(m, 16));
            m = fmaxf(m, __shfl_xor(m, 32));
            float s = 0.f;
            #pragma unroll
            for (int mi = 0; mi < 4; ++mi)
                #pragma unroll
                for (int r = 0; r < 4; ++r)
                    s += __expf(acc[mi][ni][r] - m);
            s += __shfl_xor(s, 16);
            s += __shfl_xor(s, 32);
            if (quad == 0) {
                pcm_p[(size_t)rt * N + jb + ni] = m;
                pcs_p[(size_t)rt * N + jb + ni] = s;
            }
        }
    }
}

// ---------------------------------------------------------------------------
// Combine partials into row/col softmax stats — parallel (192 x 256).
// ---------------------------------------------------------------------------
__global__ __launch_bounds__(256) void stats_combine(
    const float* __restrict__ prm_p, const float* __restrict__ prs_p,
    const float* __restrict__ prm_n, const float* __restrict__ prs_n,
    const float* __restrict__ pcm_p, const float* __restrict__ pcs_p,
    float* __restrict__ m_row, float* __restrict__ isr,
    float* __restrict__ m_col, float* __restrict__ isc)
{
    __shared__ float Ms[4][64], Ss[4][64];
    const int t = threadIdx.x;
    const int g = t >> 6, l = t & 63;
    const int idx = blockIdx.x * 64 + l;
    const int c0 = g * 16;

    float m = -3.0e38f, s = 0.f;
    if (idx < N) {
        const int i = idx;
        #pragma unroll 4
        for (int c = c0; c < c0 + 16; ++c) {
            m = fmaxf(m, prm_p[(size_t)c * N + i]);
            m = fmaxf(m, prm_n[(size_t)c * N + i]);
        }
        #pragma unroll 4
        for (int c = c0; c < c0 + 16; ++c) {
            s += prs_p[(size_t)c * N + i] * __expf(prm_p[(size_t)c * N + i] - m);
            s += prs_n[(size_t)c * N + i] * __expf(prm_n[(size_t)c * N + i] - m);
        }
    } else {
        const int mat = (idx - N) >> 12;
        const int j = idx & (N - 1);
        const float* pm = mat ? prm_n : pcm_p;
        const float* ps = mat ? prs_n : pcs_p;
        #pragma unroll 4
        for (int c = c0; c < c0 + 16; ++c)
            m = fmaxf(m, pm[(size_t)c * N + j]);
        #pragma unroll 4
        for (int c = c0; c < c0 + 16; ++c)
            s += ps[(size_t)c * N + j] * __expf(pm[(size_t)c * N + j] - m);
    }
    Ms[g][l] = m; Ss[g][l] = s;
    __syncthreads();
    if (g == 0) {
        float m0 = Ms[0][l], m1 = Ms[1][l], m2 = Ms[2][l], m3 = Ms[3][l];
        float mm = fmaxf(fmaxf(m0, m1), fmaxf(m2, m3));
        float ss = Ss[0][l] * __expf(m0 - mm) + Ss[1][l] * __expf(m1 - mm)
                 + Ss[2][l] * __expf(m2 - mm) + Ss[3][l] * __expf(m3 - mm);
        if (idx < N) {
            m_row[idx] = mm;
            isr[idx] = 1.0f / sqrtf(ss);
        } else {
            const int mat = (idx - N) >> 12;
            const int j = idx & (N - 1);
            m_col[mat * N + j] = mm;
            isc[mat * N + j] = 1.0f / sqrtf(ss);
        }
    }
}

// ---------------------------------------------------------------------------
// pv via MFMA: A fp16 tile -> P (fp32 rowsums -> sp/sn), split P (trunc) to
// bf16 hi/lo in LDS, MFMA P @ B (B = RTN-bf16 transposed [d][j]).
// B-operand d-column permutation: d-row sits in LDS row (d&7)*16+(d>>3), so
// fragment slot (ni,l16) holds d = l16*8+ni -> each lane's 8 outputs per r
// are d-contiguous: two float4 stores (was 8 scalar). XOR j-rotation keeps
// LDS conflict-free.
// ---------------------------------------------------------------------------
__global__ __launch_bounds__(256) void pv_mfma(
    const f16* __restrict__ Apos, const f16* __restrict__ Aneg,
    const u16* __restrict__ Yth, const u16* __restrict__ Xth,
    const float* __restrict__ m_row, const float* __restrict__ isr,
    const float* __restrict__ m_col, const float* __restrict__ isc,
    float* __restrict__ u_part, float* __restrict__ w_part,
    float* __restrict__ sp_arr, float* __restrict__ sn_arr)
{
    const int mat = blockIdx.z;
    const f16* Am = mat ? Aneg : Apos;
    const u16* Bh = mat ? Xth : Yth;
    const float* mc = m_col + mat * N;
    const float* ic = isc + mat * N;
    float* Cp = (mat ? w_part : u_part) + (size_t)blockIdx.y * (N * D);
    float* spn = mat ? sn_arr : sp_arr;

    __shared__ u16 BhS[128][72];
    __shared__ u16 PhS[64][72], PlS[64][72];
    __shared__ float mrS[64], isrS[64];

    const int t = threadIdx.x;
    const int w = t >> 6, lane = t & 63;
    const int quad = lane >> 4, l16 = lane & 15;
    const int bm = blockIdx.x * 64;
    const int jbase = blockIdx.y * (N / KSPLIT);
    const int arow = t >> 4;          // 0..15
    const int aj = (t & 15) << 2;     // 0..60

    if (t < 64) { mrS[t] = m_row[bm + t]; isrS[t] = isr[bm + t]; }

    f32x4 acc[8] = {};
    float rs[4] = {0.f, 0.f, 0.f, 0.f};

    for (int jt = 0; jt < (N / KSPLIT) / 64; ++jt) {
        const int j0 = jbase + jt * 64;
        __syncthreads();   // protect previous iteration's LDS reads (+ mrS init)
        #pragma unroll
        for (int p = 0; p < 4; ++p) {
            int slot = t + p * 256;
            int d = slot >> 3, joff = (slot & 7) << 3;
            int pd = ((d & 7) << 4) | (d >> 3);
            int jf = joff ^ (((pd >> 4) & 7) << 3);
            *(u16x8*)&BhS[pd][jf] = *(const u16x8*)(Bh + (size_t)d * N + j0 + joff);
        }
        float4 mcv = *(const float4*)(mc + j0 + aj);
        float4 icv = *(const float4*)(ic + j0 + aj);
        #pragma unroll
        for (int s = 0; s < 4; ++s) {
            int row = arow + s * 16;
            f16x4 av = *(const f16x4*)(Am + (size_t)(bm + row) * N + j0 + aj);
            float mr = mrS[row], sr = isrS[row];
            float p0 = __expf((float)av.x - 0.5f * (mr + mcv.x)) * (sr * icv.x);
            float p1 = __expf((float)av.y - 0.5f * (mr + mcv.y)) * (sr * icv.y);
            float p2 = __expf((float)av.z - 0.5f * (mr + mcv.z)) * (sr * icv.z);
            float p3 = __expf((float)av.w - 0.5f * (mr + mcv.w)) * (sr * icv.w);
            rs[s] += p0 + p1 + p2 + p3;
            ushort4 hv, lv;
            split1_trunc(p0, hv.x, lv.x); split1_trunc(p1, hv.y, lv.y);
            split1_trunc(p2, hv.z, lv.z); split1_trunc(p3, hv.w, lv.w);
            *(ushort4*)&PhS[row][aj] = hv;
            *(ushort4*)&PlS[row][aj] = lv;
        }
        __syncthreads();
        #pragma unroll
        for (int ks = 0; ks < 2; ++ks) {
            const int kk = ks * 32 + quad * 8;
            bf16x8 ph = *(const bf16x8*)&PhS[w * 16 + l16][kk];
            bf16x8 pl = *(const bf16x8*)&PlS[w * 16 + l16][kk];
            #pragma unroll
            for (int ni = 0; ni < 8; ++ni) {
                bf16x8 bh = *(const bf16x8*)
                    &BhS[ni * 16 + l16][kk ^ ((ni & 7) << 3)];
                acc[ni] = MFMA(ph, bh, acc[ni]);
                acc[ni] = MFMA(pl, bh, acc[ni]);
            }
        }
    }
    // lane's 8 d-cols are contiguous: l16*8 .. +7
    #pragma unroll
    for (int r = 0; r < 4; ++r) {
        int row = w * 16 + quad * 4 + r;
        size_t off = (size_t)(bm + row) * D + (l16 << 3);
        *(float4*)(Cp + off) =
            make_float4(acc[0][r], acc[1][r], acc[2][r], acc[3][r]);
        *(float4*)(Cp + off + 4) =
            make_float4(acc[4][r], acc[5][r], acc[6][r], acc[7][r]);
    }
    #pragma unroll
    for (int s = 0; s < 4; ++s) {
        float v = rs[s];
        v += __shfl_xor(v, 1); v += __shfl_xor(v, 2);
        v += __shfl_xor(v, 4); v += __shfl_xor(v, 8);
        if (l16 == 0) atomicAdd(&spn[bm + arow + s * 16], v);
    }
}

// ---------------------------------------------------------------------------
// Sum split-K partials, V = sn*u - sp*sn*w, accumulate sum(V^2).
// ---------------------------------------------------------------------------
__global__ __launch_bounds__(256) void final_reduce(const float* __restrict__ u_part,
    const float* __restrict__ w_part, const float* __restrict__ sp_arr,
    const float* __restrict__ sn_arr, double* __restrict__ acc_out)
{
    __shared__ float red[256];
    const int t = threadIdx.x;
    const int idx = blockIdx.x * 256 + t;
    float u = 0.f, w = 0.f;
    #pragma unroll
    for (int c = 0; c < KSPLIT; ++c) {
        u += u_part[(size_t)c * (N * D) + idx];
        w += w_part[(size_t)c * (N * D) + idx];
    }
    const int i = idx >> 7;
    const float sn = sn_arr[i];
    const float v = sn * u - sp_arr[i] * sn * w;
    red[t] = v * v; __syncthreads();
    for (int s = 128; s > 0; s >>= 1) { if (t < s) red[t] += red[t + s]; __syncthreads(); }
    if (!t) atomicAdd(acc_out, (double)red[0]);
}

__global__ void finalize(const double* __restrict__ acc, float* __restrict__ out)
{
    out[0] = (float)(*acc * (1.0 / ((double)N * (double)D)));
}

// ---------------------------------------------------------------------------
extern "C" void kernel_launch(void* const* d_in, const int* in_sizes, int n_in,
                              void* d_out, int out_size, void* d_ws, size_t ws_size,
                              hipStream_t stream)
{
    const float* y_pos = (const float*)d_in[0];
    const float* eps   = (const float*)d_in[1];
    const float* W_in  = (const float*)d_in[2];
    const float* b_in  = (const float*)d_in[3];
    const float* W_blk = (const float*)d_in[4];
    const float* b_blk = (const float*)d_in[5];
    const float* W_out = (const float*)d_in[6];
    const float* b_out = (const float*)d_in[7];
    float* out = (float*)d_out;
    (void)in_sizes; (void)n_in; (void)out_size; (void)ws_size;

    char* p = (char*)d_ws;
    auto alloc = [&](size_t bytes) {
        char* r = p;
        p += (bytes + 255) & ~(size_t)255;
        return r;
    };
    // --- small arrays ---
    double* acc  = (double*)alloc(8);
    float* sp     = (float*)alloc(N * 4);
    float* sn     = (float*)alloc(N * 4);
    float* m_row  = (float*)alloc(N * 4);
    float* isr    = (float*)alloc(N * 4);
    float* m_col  = (float*)alloc(2 * N * 4);
    float* isc    = (float*)alloc(2 * N * 4);
    float* nx     = (float*)alloc(N * 4);
    float* ny     = (float*)alloc(N * 4);
    // --- eh/el (2 MB; only live through the first gen layer) ---
    u16* eh = (u16*)alloc((size_t)N * D * 2);
    u16* el = (u16*)alloc((size_t)N * D * 2);
    // --- xo fp32 + bf16 x/y arrays ---
    float* xo  = (float*)alloc((size_t)N * D * 4);
    u16* xh    = (u16*)alloc((size_t)N * D * 2);
    u16* xl    = (u16*)alloc((size_t)N * D * 2);
    u16* xth   = (u16*)alloc((size_t)N * D * 2);
    u16* yh    = (u16*)alloc((size_t)N * D * 2);
    u16* yl    = (u16*)alloc((size_t)N * D * 2);
    u16* yth   = (u16*)alloc((size_t)N * D * 2);
    // --- generator region (21 MB): activations + weights; later aliased by
    //     stats partials (6 MB) then u/w_part (16 MB) ---
    char* genreg = alloc((size_t)(4 * (size_t)N * H * 2
                                + 2 * (size_t)H * D * 2
                                + 2 * (size_t)4 * H * H * 2
                                + 2 * (size_t)D * H * 2));
    u16* x0h = (u16*)genreg;
    u16* x0l = x0h + (size_t)N * H;
    u16* x1h = x0l + (size_t)N * H;
    u16* x1l = x1h + (size_t)N * H;
    u16* wih = x1l + (size_t)N * H;
    u16* wil = wih + (size_t)H * D;
    u16* wbh = wil + (size_t)H * D;
    u16* wbl = wbh + (size_t)4 * H * H;
    u16* woh = wbl + (size_t)4 * H * H;
    u16* wol = woh + (size_t)D * H;
    // aliases (disjoint lifetimes, stream-ordered):
    float* prm_p = (float*)genreg;                 // 64*N each = 1 MB
    float* prs_p = prm_p + 64 * N;
    float* prm_n = prs_p + 64 * N;
    float* prs_n = prm_n + 64 * N;
    float* pcm_p = prs_n + 64 * N;
    float* pcs_p = pcm_p + 64 * N;                 // ends at 6 MB
    float* u_part = (float*)genreg;                // KSPLIT*N*D = 8 MB
    float* w_part = u_part + (size_t)KSPLIT * N * D;
    // --- the big ones (64 MB, fp16) ---
    f16* Apos = (f16*)alloc((size_t)N * N * 2);
    f16* Aneg = (f16*)alloc((size_t)N * N * 2);

    // --- split inputs/weights to bf16 hi/lo (RTN) + workspace init (y==5) ---
    SplitArgs sa;
    sa.d[0] = { eps,   eh,  el,  N * D };
    sa.d[1] = { y_pos, yh,  yl,  N * D };
    sa.d[2] = { W_in,  wih, wil, H * D };
    sa.d[3] = { W_blk, wbh, wbl, 4 * H * H };
    sa.d[4] = { W_out, woh, wol, D * H };
    split_multi<<<dim3(1024, 6), 256, 0, stream>>>(sa, acc, sp, sn, nx, ny);

    // --- generator (MFMA, act hi/lo x W-RTN, 64x64 blocks) ---
    dim3 gh(H / 64, N / 64);
    gen_gemm<<<gh, 128, 0, stream>>>(eh, el, wih, b_in,
                                     nullptr, x0h, x0l, N, H, D, 0, 0);
    gen_gemm<<<gh, 128, 0, stream>>>(x0h, x0l, wbh + 0 * H * H,
                                     b_blk + 0 * H, nullptr, x1h, x1l, N, H, H, 1, 0);
    gen_gemm<<<gh, 128, 0, stream>>>(x1h, x1l, wbh + 1 * H * H,
                                     b_blk + 1 * H, nullptr, x0h, x0l, N, H, H, 1, 0);
    gen_gemm<<<gh, 128, 0, stream>>>(x0h, x0l, wbh + 2 * H * H,
                                     b_blk + 2 * H, nullptr, x1h, x1l, N, H, H, 1, 0);
    gen_gemm<<<gh, 128, 0, stream>>>(x1h, x1l, wbh + 3 * H * H,
                                     b_blk + 3 * H, nullptr, x0h, x0l, N, H, H, 1, 0);
    gen_gemm<<<dim3(D / 64, N / 64), 128, 0, stream>>>(x0h, x0l, woh, b_out,
                                     xo, xh, xl, N, D, H, 0, 1);

    // --- RTN transposes + fused row norms ---
    transpose_rtn<<<dim3(N / 32, D / 32, 2), 256, 0, stream>>>(
        xo, y_pos, xth, yth, nx, ny);

    // --- distance matrices (fp16, single-bf16 MFMA) + fused stats ---
    dist_fused<<<dim3(N / 128, N / 128, 2), 256, 0, stream>>>(
        xh, yh, nx, ny, Apos, Aneg,
        prm_p, prs_p, pcm_p, pcs_p, prm_n, prs_n);

    // --- combine partials into m_row/isr, m_col/isc (parallel) ---
    stats_combine<<<192, 256, 0, stream>>>(prm_p, prs_p, prm_n, prs_n,
                                           pcm_p, pcs_p,
                                           m_row, isr, m_col, isc);

    // --- P@V via MFMA (P built on the fly; sp/sn fp32 via atomics) ---
    pv_mfma<<<dim3(N / 64, KSPLIT, 2), 256, 0, stream>>>(Apos, Aneg,
        yth, xth, m_row, isr, m_col, isc, u_part, w_part, sp, sn);

    // --- combine partials, V^2 reduction ---
    final_reduce<<<(N * D) / 256, 256, 0, stream>>>(u_part, w_part, sp, sn, acc);
    finalize<<<1, 1, 0, stream>>>(acc, out);
}

// Round 18
// 326.412 us; speedup vs baseline: 1.0606x; 1.0606x over previous
//
#include <hip/hip_runtime.h>
#include <math.h>

#define N 4096
#define D 128
#define H 512
#define INV_T 5.0f
#define KSPLIT 4

typedef short bf16x8 __attribute__((ext_vector_type(8)));
typedef float f32x4 __attribute__((ext_vector_type(4)));
typedef unsigned short u16x8 __attribute__((ext_vector_type(8)));
typedef unsigned short u16;
typedef _Float16 f16;
typedef _Float16 f16x4 __attribute__((ext_vector_type(4)));

#define MFMA(a, b, c) __builtin_amdgcn_mfma_f32_16x16x32_bf16((a), (b), (c), 0, 0, 0)

__device__ __forceinline__ float bf2f(u16 h)
{
    return __uint_as_float(((unsigned)h) << 16);
}

// Round-to-nearest bf16 (unbiased) — for operands whose hi is used ALONE.
__device__ __forceinline__ u16 rtn_bf16(float v)
{
    unsigned u = __float_as_uint(v);
    return (u16)((u + 0x7FFFu + ((u >> 16) & 1u)) >> 16);
}

// RTN split (hi usable alone; lo compensates). Cold paths + last gen layer.
__device__ __forceinline__ void split1(float v, u16& h, u16& l)
{
    u16 hh = rtn_bf16(v);
    float r = v - bf2f(hh);
    h = hh;
    l = rtn_bf16(r);
}

// Cheap truncation split (3 ops); hi+lo pair accuracy identical.
__device__ __forceinline__ void split1_trunc(float v, u16& h, u16& l)
{
    unsigned bv = __float_as_uint(v);
    unsigned hb = bv & 0xFFFF0000u;
    float r = v - __uint_as_float(hb);
    h = (u16)(hb >> 16);
    l = (u16)(__float_as_uint(r) >> 16);
}

// ---------------------------------------------------------------------------
// One-shot splitter for 5 flat fp32 arrays -> bf16 hi/lo (RTN, cold) and,
// on the y==5 plane, workspace init (acc/sp/sn/nx/ny).
// ---------------------------------------------------------------------------
struct SplitDesc { const float* src; u16* h; u16* l; int n; };
struct SplitArgs { SplitDesc d[5]; };

__global__ __launch_bounds__(256) void split_multi(SplitArgs args,
    double* acc, float* sp, float* sn, float* nx, float* ny)
{
    if (blockIdx.y == 5) {
        int idx = blockIdx.x * 256 + threadIdx.x;
        if (idx == 0) *acc = 0.0;
        if (idx < N) { sp[idx] = 0.f; sn[idx] = 0.f; nx[idx] = 0.f; ny[idx] = 0.f; }
        return;
    }
    SplitDesc de = args.d[blockIdx.y];
    int idx = (blockIdx.x * 256 + threadIdx.x) * 4;
    if (idx >= de.n) return;
    float4 v = *(const float4*)(de.src + idx);
    ushort4 hv, lv;
    split1(v.x, hv.x, lv.x); split1(v.y, hv.y, lv.y);
    split1(v.z, hv.z, lv.z); split1(v.w, hv.w, lv.w);
    *(ushort4*)(de.h + idx) = hv;
    *(ushort4*)(de.l + idx) = lv;
}

// ---------------------------------------------------------------------------
// Transpose + RTN-bf16 + fused row-norm partials (atomicAdd into nx/ny).
// ---------------------------------------------------------------------------
__global__ __launch_bounds__(256) void transpose_rtn(
    const float* __restrict__ X, const float* __restrict__ Y,
    u16* __restrict__ Xth, u16* __restrict__ Yth,
    float* __restrict__ nx, float* __restrict__ ny)
{
    const float* src = blockIdx.z ? Y : X;
    u16* th = blockIdx.z ? Yth : Xth;
    float* nrm = blockIdx.z ? ny : nx;
    __shared__ float tile[32][33];
    const int t = threadIdx.x;
    const int r0 = blockIdx.x * 32, c0 = blockIdx.y * 32;
    {
        int rit = t >> 3, coff = (t & 7) * 4;
        float4 v = *(const float4*)(src + (size_t)(r0 + rit) * D + c0 + coff);
        tile[rit][coff + 0] = v.x; tile[rit][coff + 1] = v.y;
        tile[rit][coff + 2] = v.z; tile[rit][coff + 3] = v.w;
        float sq = v.x * v.x + v.y * v.y + v.z * v.z + v.w * v.w;
        sq += __shfl_xor(sq, 1);
        sq += __shfl_xor(sq, 2);
        sq += __shfl_xor(sq, 4);
        if ((t & 7) == 0) atomicAdd(&nrm[r0 + rit], sq);
    }
    __syncthreads();
    {
        int cit = t >> 3, roff = (t & 7) * 4;
        ushort4 hv;
        hv.x = rtn_bf16(tile[roff + 0][cit]);
        hv.y = rtn_bf16(tile[roff + 1][cit]);
        hv.z = rtn_bf16(tile[roff + 2][cit]);
        hv.w = rtn_bf16(tile[roff + 3][cit]);
        *(ushort4*)(th + (size_t)(c0 + cit) * N + r0 + roff) = hv;
    }
}

// ---------------------------------------------------------------------------
// Generator GEMM: A = activations hi/lo bf16 pair, B = weights single RTN
// bf16. Tile 64x64, BK=32, 128 threads. rtn_out=1 on the last layer only.
// ---------------------------------------------------------------------------
__global__ __launch_bounds__(128) void gen_gemm(
    const u16* __restrict__ Ah, const u16* __restrict__ Al,
    const u16* __restrict__ Bh,
    const float* __restrict__ bias,
    float* __restrict__ C, u16* __restrict__ Ch, u16* __restrict__ Cl,
    int M, int Nn, int K, int resid, int rtn_out)
{
    __shared__ u16 AhS[64][40], AlS[64][40];
    __shared__ u16 BhS[64][40];
    const int t = threadIdx.x;
    const int w = t >> 6, lane = t & 63;
    const int quad = lane >> 4, l16 = lane & 15;
    const int bm = blockIdx.y * 64, bn = blockIdx.x * 64;
    f32x4 acc[2][4] = {};

    for (int k0 = 0; k0 < K; k0 += 32) {
        __syncthreads();
        #pragma unroll
        for (int p = 0; p < 2; ++p) {
            int slot = t + p * 128;
            int row = slot >> 2, koff = (slot & 3) << 3;
            size_t ga = (size_t)(bm + row) * K + k0 + koff;
            size_t gb = (size_t)(bn + row) * K + k0 + koff;
            *(u16x8*)&AhS[row][koff] = *(const u16x8*)(Ah + ga);
            *(u16x8*)&AlS[row][koff] = *(const u16x8*)(Al + ga);
            *(u16x8*)&BhS[row][koff] = *(const u16x8*)(Bh + gb);
        }
        __syncthreads();
        bf16x8 af[2], alf[2], bhf[4];
        #pragma unroll
        for (int mi = 0; mi < 2; ++mi) {
            int r = w * 32 + mi * 16 + l16;
            af[mi]  = *(const bf16x8*)&AhS[r][quad * 8];
            alf[mi] = *(const bf16x8*)&AlS[r][quad * 8];
        }
        #pragma unroll
        for (int ni = 0; ni < 4; ++ni)
            bhf[ni] = *(const bf16x8*)&BhS[ni * 16 + l16][quad * 8];
        #pragma unroll
        for (int mi = 0; mi < 2; ++mi)
            #pragma unroll
            for (int ni = 0; ni < 4; ++ni) {
                acc[mi][ni] = MFMA(af[mi], bhf[ni], acc[mi][ni]);
                acc[mi][ni] = MFMA(alf[mi], bhf[ni], acc[mi][ni]);
            }
    }
    #pragma unroll
    for (int mi = 0; mi < 2; ++mi)
        #pragma unroll
        for (int ni = 0; ni < 4; ++ni)
            #pragma unroll
            for (int r = 0; r < 4; ++r) {
                int gm = bm + w * 32 + mi * 16 + quad * 4 + r;
                int gn = bn + ni * 16 + l16;
                float v = acc[mi][ni][r] + bias[gn];
                if (resid) {
                    size_t o2 = (size_t)gm * K + gn;
                    float prev = bf2f(Ah[o2]) + bf2f(Al[o2]);
                    v = prev + fmaxf(v, 0.0f);
                }
                size_t o = (size_t)gm * Nn + gn;
                if (C) C[o] = v;
                u16 hh, ll;
                if (rtn_out) split1(v, hh, ll);
                else         split1_trunc(v, hh, ll);
                Ch[o] = hh; Cl[o] = ll;
            }
}

// ---------------------------------------------------------------------------
// Distance via SINGLE RTN-bf16 MFMA, fused stats, pos+neg merged. A fp16.
// B-operand column permutation (R17, proven): fragment slot (ni,l16) holds
// j = l16*4+ni -> one f16x4 store per (mi,r), ny as one float4 load.
// XOR k-rotation keeps LDS conflict-free.
// ---------------------------------------------------------------------------
__global__ __launch_bounds__(256) void dist_fused(
    const u16* __restrict__ Xh, const u16* __restrict__ Yh,
    const float* __restrict__ nx, const float* __restrict__ ny,
    f16* __restrict__ Apos, f16* __restrict__ Aneg,
    float* __restrict__ prm_p, float* __restrict__ prs_p,
    float* __restrict__ pcm_p, float* __restrict__ pcs_p,
    float* __restrict__ prm_n, float* __restrict__ prs_n)
{
    const int mat = blockIdx.z;                // 0: X vs Y ; 1: X vs X
    const u16* Bhp = mat ? Xh : Yh;
    const float* nb = mat ? nx : ny;
    f16* Out = mat ? Aneg : Apos;
    float* prm = mat ? prm_n : prm_p;
    float* prs = mat ? prs_n : prs_p;

    __shared__ u16 XhS[128][40], YhS[128][40];
    const int t = threadIdx.x;
    const int w = t >> 6, lane = t & 63;
    const int quad = lane >> 4, l16 = lane & 15;
    const int wm = w & 1, wn = w >> 1;
    const int bm = blockIdx.y * 128, bn = blockIdx.x * 128;
    f32x4 acc[4][4] = {};

    for (int k0 = 0; k0 < D; k0 += 32) {
        __syncthreads();
        #pragma unroll
        for (int p = 0; p < 2; ++p) {
            int slot = t + p * 256;            // 512 slots = 128 rows x 4 octets
            int row = slot >> 2, koff = (slot & 3) << 3;
            *(u16x8*)&XhS[row][koff] =
                *(const u16x8*)(Xh + (size_t)(bm + row) * D + k0 + koff);
            int pr = ((row & 3) << 4) | ((row & 63) >> 2) | (row & 64);
            int kf = koff ^ (((pr >> 4) & 3) << 3);
            *(u16x8*)&YhS[pr][kf] =
                *(const u16x8*)(Bhp + (size_t)(bn + row) * D + k0 + koff);
        }
        __syncthreads();
        bf16x8 af[4], bhf[4];
        #pragma unroll
        for (int mi = 0; mi < 4; ++mi)
            af[mi] = *(const bf16x8*)&XhS[wm * 64 + mi * 16 + l16][quad * 8];
        #pragma unroll
        for (int ni = 0; ni < 4; ++ni)
            bhf[ni] = *(const bf16x8*)
                &YhS[wn * 64 + ni * 16 + l16][(quad * 8) ^ ((ni & 3) << 3)];
        #pragma unroll
        for (int mi = 0; mi < 4; ++mi)
            #pragma unroll
            for (int ni = 0; ni < 4; ++ni)
                acc[mi][ni] = MFMA(af[mi], bhf[ni], acc[mi][ni]);
    }
    // lane's 4 j's are contiguous: jb..jb+3
    const int jb = bn + wn * 64 + (l16 << 2);
    const float4 nyv = *(const float4*)(nb + jb);
    const float nyl[4] = {nyv.x, nyv.y, nyv.z, nyv.w};
    // --- transform in place + vector store ---
    #pragma unroll
    for (int mi = 0; mi < 4; ++mi)
        #pragma unroll
        for (int r = 0; r < 4; ++r) {
            int gm = bm + wm * 64 + mi * 16 + quad * 4 + r;
            float nxm = nx[gm];
            f16x4 ov;
            #pragma unroll
            for (int ni = 0; ni < 4; ++ni) {
                float d2 = nxm + nyl[ni] - 2.0f * acc[mi][ni][r];
                float a = -sqrtf(fmaxf(d2, 0.0f)) * INV_T;
                if (mat && gm == jb + ni) a = -5.0e6f;
                acc[mi][ni][r] = a;
                ov[ni] = (f16)a;
            }
            *(f16x4*)(Out + (size_t)gm * N + jb) = ov;
        }
    // --- row partials: per (mi,r), reduce over ni (in-lane) + l16 (shfl) ---
    const int ct = blockIdx.x * 2 + wn;
    #pragma unroll
    for (int mi = 0; mi < 4; ++mi)
        #pragma unroll
        for (int r = 0; r < 4; ++r) {
            float m = fmaxf(fmaxf(acc[mi][0][r], acc[mi][1][r]),
                            fmaxf(acc[mi][2][r], acc[mi][3][r]));
            m = fmaxf(m, __shfl_xor(m, 1));
            m = fmaxf(m, __shfl_xor(m, 2));
            m = fmaxf(m, __shfl_xor(m, 4));
            m = fmaxf(m, __shfl_xor(m, 8));
            float s = __expf(acc[mi][0][r] - m) + __expf(acc[mi][1][r] - m)
                    + __expf(acc[mi][2][r] - m) + __expf(acc[mi][3][r] - m);
            s += __shfl_xor(s, 1); s += __shfl_xor(s, 2);
            s += __shfl_xor(s, 4); s += __shfl_xor(s, 8);
            if (l16 == 0) {
                int grow = bm + wm * 64 + mi * 16 + quad * 4 + r;
                prm[(size_t)ct * N + grow] = m;
                prs[(size_t)ct * N + grow] = s;
            }
        }
    // --- col partials (pos only): per ni, in-lane over (mi,r) + quad shfl ---
    if (mat == 0) {
        const int rt = blockIdx.y * 2 + wm;
        #pragma unroll
        for (int ni = 0; ni < 4; ++ni) {
            float m = -3.0e38f;
            #pragma unroll
            for (int mi = 0; mi < 4; ++mi)
                #pragma unroll
                for (int r = 0; r < 4; ++r)
                    m = fmaxf(m, acc[mi][ni][r]);
            m = fmaxf(m, __shfl_xor(m, 16));
            m = fmaxf(m, __shfl_xor(m, 32));
            float s = 0.f;
            #pragma unroll
            for (int mi = 0; mi < 4; ++mi)
                #pragma unroll
                for (int r = 0; r < 4; ++r)
                    s += __expf(acc[mi][ni][r] - m);
            s += __shfl_xor(s, 16);
            s += __shfl_xor(s, 32);
            if (quad == 0) {
                pcm_p[(size_t)rt * N + jb + ni] = m;
                pcs_p[(size_t)rt * N + jb + ni] = s;
            }
        }
    }
}

// ---------------------------------------------------------------------------
// Combine partials into row/col softmax stats — parallel (192 x 256).
// ---------------------------------------------------------------------------
__global__ __launch_bounds__(256) void stats_combine(
    const float* __restrict__ prm_p, const float* __restrict__ prs_p,
    const float* __restrict__ prm_n, const float* __restrict__ prs_n,
    const float* __restrict__ pcm_p, const float* __restrict__ pcs_p,
    float* __restrict__ m_row, float* __restrict__ isr,
    float* __restrict__ m_col, float* __restrict__ isc)
{
    __shared__ float Ms[4][64], Ss[4][64];
    const int t = threadIdx.x;
    const int g = t >> 6, l = t & 63;
    const int idx = blockIdx.x * 64 + l;
    const int c0 = g * 16;

    float m = -3.0e38f, s = 0.f;
    if (idx < N) {
        const int i = idx;
        #pragma unroll 4
        for (int c = c0; c < c0 + 16; ++c) {
            m = fmaxf(m, prm_p[(size_t)c * N + i]);
            m = fmaxf(m, prm_n[(size_t)c * N + i]);
        }
        #pragma unroll 4
        for (int c = c0; c < c0 + 16; ++c) {
            s += prs_p[(size_t)c * N + i] * __expf(prm_p[(size_t)c * N + i] - m);
            s += prs_n[(size_t)c * N + i] * __expf(prm_n[(size_t)c * N + i] - m);
        }
    } else {
        const int mat = (idx - N) >> 12;
        const int j = idx & (N - 1);
        const float* pm = mat ? prm_n : pcm_p;
        const float* ps = mat ? prs_n : pcs_p;
        #pragma unroll 4
        for (int c = c0; c < c0 + 16; ++c)
            m = fmaxf(m, pm[(size_t)c * N + j]);
        #pragma unroll 4
        for (int c = c0; c < c0 + 16; ++c)
            s += ps[(size_t)c * N + j] * __expf(pm[(size_t)c * N + j] - m);
    }
    Ms[g][l] = m; Ss[g][l] = s;
    __syncthreads();
    if (g == 0) {
        float m0 = Ms[0][l], m1 = Ms[1][l], m2 = Ms[2][l], m3 = Ms[3][l];
        float mm = fmaxf(fmaxf(m0, m1), fmaxf(m2, m3));
        float ss = Ss[0][l] * __expf(m0 - mm) + Ss[1][l] * __expf(m1 - mm)
                 + Ss[2][l] * __expf(m2 - mm) + Ss[3][l] * __expf(m3 - mm);
        if (idx < N) {
            m_row[idx] = mm;
            isr[idx] = 1.0f / sqrtf(ss);
        } else {
            const int mat = (idx - N) >> 12;
            const int j = idx & (N - 1);
            m_col[mat * N + j] = mm;
            isc[mat * N + j] = 1.0f / sqrtf(ss);
        }
    }
}

// ---------------------------------------------------------------------------
// pv via MFMA (R16 proven form): A fp16 tile -> P (fp32 rowsums -> sp/sn),
// split P (trunc) to bf16 hi/lo in LDS, MFMA P @ B (B = RTN-bf16 transposed
// [d][j], hi only). Unpermuted staging; scalar C-stores (lane-coalesced).
// ---------------------------------------------------------------------------
__global__ __launch_bounds__(256) void pv_mfma(
    const f16* __restrict__ Apos, const f16* __restrict__ Aneg,
    const u16* __restrict__ Yth, const u16* __restrict__ Xth,
    const float* __restrict__ m_row, const float* __restrict__ isr,
    const float* __restrict__ m_col, const float* __restrict__ isc,
    float* __restrict__ u_part, float* __restrict__ w_part,
    float* __restrict__ sp_arr, float* __restrict__ sn_arr)
{
    const int mat = blockIdx.z;
    const f16* Am = mat ? Aneg : Apos;
    const u16* Bh = mat ? Xth : Yth;
    const float* mc = m_col + mat * N;
    const float* ic = isc + mat * N;
    float* Cp = (mat ? w_part : u_part) + (size_t)blockIdx.y * (N * D);
    float* spn = mat ? sn_arr : sp_arr;

    __shared__ u16 BhS[128][72];
    __shared__ u16 PhS[64][72], PlS[64][72];
    __shared__ float mrS[64], isrS[64];

    const int t = threadIdx.x;
    const int w = t >> 6, lane = t & 63;
    const int quad = lane >> 4, l16 = lane & 15;
    const int bm = blockIdx.x * 64;
    const int jbase = blockIdx.y * (N / KSPLIT);
    const int arow = t >> 4;          // 0..15
    const int aj = (t & 15) << 2;     // 0..60

    if (t < 64) { mrS[t] = m_row[bm + t]; isrS[t] = isr[bm + t]; }

    f32x4 acc[8] = {};
    float rs[4] = {0.f, 0.f, 0.f, 0.f};

    for (int jt = 0; jt < (N / KSPLIT) / 64; ++jt) {
        const int j0 = jbase + jt * 64;
        __syncthreads();   // protect previous iteration's LDS reads (+ mrS init)
        #pragma unroll
        for (int p = 0; p < 4; ++p) {
            int slot = t + p * 256;
            int d = slot >> 3, joff = (slot & 7) << 3;
            *(u16x8*)&BhS[d][joff] = *(const u16x8*)(Bh + (size_t)d * N + j0 + joff);
        }
        float4 mcv = *(const float4*)(mc + j0 + aj);
        float4 icv = *(const float4*)(ic + j0 + aj);
        #pragma unroll
        for (int s = 0; s < 4; ++s) {
            int row = arow + s * 16;
            f16x4 av = *(const f16x4*)(Am + (size_t)(bm + row) * N + j0 + aj);
            float mr = mrS[row], sr = isrS[row];
            float p0 = __expf((float)av.x - 0.5f * (mr + mcv.x)) * (sr * icv.x);
            float p1 = __expf((float)av.y - 0.5f * (mr + mcv.y)) * (sr * icv.y);
            float p2 = __expf((float)av.z - 0.5f * (mr + mcv.z)) * (sr * icv.z);
            float p3 = __expf((float)av.w - 0.5f * (mr + mcv.w)) * (sr * icv.w);
            rs[s] += p0 + p1 + p2 + p3;
            ushort4 hv, lv;
            split1_trunc(p0, hv.x, lv.x); split1_trunc(p1, hv.y, lv.y);
            split1_trunc(p2, hv.z, lv.z); split1_trunc(p3, hv.w, lv.w);
            *(ushort4*)&PhS[row][aj] = hv;
            *(ushort4*)&PlS[row][aj] = lv;
        }
        __syncthreads();
        #pragma unroll
        for (int ks = 0; ks < 2; ++ks) {
            const int kk = ks * 32 + quad * 8;
            bf16x8 ph = *(const bf16x8*)&PhS[w * 16 + l16][kk];
            bf16x8 pl = *(const bf16x8*)&PlS[w * 16 + l16][kk];
            #pragma unroll
            for (int ni = 0; ni < 8; ++ni) {
                bf16x8 bh = *(const bf16x8*)&BhS[ni * 16 + l16][kk];
                acc[ni] = MFMA(ph, bh, acc[ni]);
                acc[ni] = MFMA(pl, bh, acc[ni]);
            }
        }
    }
    #pragma unroll
    for (int ni = 0; ni < 8; ++ni)
        #pragma unroll
        for (int r = 0; r < 4; ++r) {
            int row = w * 16 + quad * 4 + r;
            int col = ni * 16 + l16;
            Cp[(size_t)(bm + row) * D + col] = acc[ni][r];
        }
    #pragma unroll
    for (int s = 0; s < 4; ++s) {
        float v = rs[s];
        v += __shfl_xor(v, 1); v += __shfl_xor(v, 2);
        v += __shfl_xor(v, 4); v += __shfl_xor(v, 8);
        if (l16 == 0) atomicAdd(&spn[bm + arow + s * 16], v);
    }
}

// ---------------------------------------------------------------------------
// Sum split-K partials, V = sn*u - sp*sn*w, accumulate sum(V^2).
// ---------------------------------------------------------------------------
__global__ __launch_bounds__(256) void final_reduce(const float* __restrict__ u_part,
    const float* __restrict__ w_part, const float* __restrict__ sp_arr,
    const float* __restrict__ sn_arr, double* __restrict__ acc_out)
{
    __shared__ float red[256];
    const int t = threadIdx.x;
    const int idx = blockIdx.x * 256 + t;
    float u = 0.f, w = 0.f;
    #pragma unroll
    for (int c = 0; c < KSPLIT; ++c) {
        u += u_part[(size_t)c * (N * D) + idx];
        w += w_part[(size_t)c * (N * D) + idx];
    }
    const int i = idx >> 7;
    const float sn = sn_arr[i];
    const float v = sn * u - sp_arr[i] * sn * w;
    red[t] = v * v; __syncthreads();
    for (int s = 128; s > 0; s >>= 1) { if (t < s) red[t] += red[t + s]; __syncthreads(); }
    if (!t) atomicAdd(acc_out, (double)red[0]);
}

__global__ void finalize(const double* __restrict__ acc, float* __restrict__ out)
{
    out[0] = (float)(*acc * (1.0 / ((double)N * (double)D)));
}

// ---------------------------------------------------------------------------
extern "C" void kernel_launch(void* const* d_in, const int* in_sizes, int n_in,
                              void* d_out, int out_size, void* d_ws, size_t ws_size,
                              hipStream_t stream)
{
    const float* y_pos = (const float*)d_in[0];
    const float* eps   = (const float*)d_in[1];
    const float* W_in  = (const float*)d_in[2];
    const float* b_in  = (const float*)d_in[3];
    const float* W_blk = (const float*)d_in[4];
    const float* b_blk = (const float*)d_in[5];
    const float* W_out = (const float*)d_in[6];
    const float* b_out = (const float*)d_in[7];
    float* out = (float*)d_out;
    (void)in_sizes; (void)n_in; (void)out_size; (void)ws_size;

    char* p = (char*)d_ws;
    auto alloc = [&](size_t bytes) {
        char* r = p;
        p += (bytes + 255) & ~(size_t)255;
        return r;
    };
    // --- small arrays ---
    double* acc  = (double*)alloc(8);
    float* sp     = (float*)alloc(N * 4);
    float* sn     = (float*)alloc(N * 4);
    float* m_row  = (float*)alloc(N * 4);
    float* isr    = (float*)alloc(N * 4);
    float* m_col  = (float*)alloc(2 * N * 4);
    float* isc    = (float*)alloc(2 * N * 4);
    float* nx     = (float*)alloc(N * 4);
    float* ny     = (float*)alloc(N * 4);
    // --- eh/el (2 MB; only live through the first gen layer) ---
    u16* eh = (u16*)alloc((size_t)N * D * 2);
    u16* el = (u16*)alloc((size_t)N * D * 2);
    // --- xo fp32 + bf16 x/y arrays ---
    float* xo  = (float*)alloc((size_t)N * D * 4);
    u16* xh    = (u16*)alloc((size_t)N * D * 2);
    u16* xl    = (u16*)alloc((size_t)N * D * 2);
    u16* xth   = (u16*)alloc((size_t)N * D * 2);
    u16* yh    = (u16*)alloc((size_t)N * D * 2);
    u16* yl    = (u16*)alloc((size_t)N * D * 2);
    u16* yth   = (u16*)alloc((size_t)N * D * 2);
    // --- generator region (21 MB): activations + weights; later aliased by
    //     stats partials (6 MB) then u/w_part (16 MB) ---
    char* genreg = alloc((size_t)(4 * (size_t)N * H * 2
                                + 2 * (size_t)H * D * 2
                                + 2 * (size_t)4 * H * H * 2
                                + 2 * (size_t)D * H * 2));
    u16* x0h = (u16*)genreg;
    u16* x0l = x0h + (size_t)N * H;
    u16* x1h = x0l + (size_t)N * H;
    u16* x1l = x1h + (size_t)N * H;
    u16* wih = x1l + (size_t)N * H;
    u16* wil = wih + (size_t)H * D;
    u16* wbh = wil + (size_t)H * D;
    u16* wbl = wbh + (size_t)4 * H * H;
    u16* woh = wbl + (size_t)4 * H * H;
    u16* wol = woh + (size_t)D * H;
    // aliases (disjoint lifetimes, stream-ordered):
    float* prm_p = (float*)genreg;                 // 64*N each = 1 MB
    float* prs_p = prm_p + 64 * N;
    float* prm_n = prs_p + 64 * N;
    float* prs_n = prm_n + 64 * N;
    float* pcm_p = prs_n + 64 * N;
    float* pcs_p = pcm_p + 64 * N;                 // ends at 6 MB
    float* u_part = (float*)genreg;                // KSPLIT*N*D = 8 MB
    float* w_part = u_part + (size_t)KSPLIT * N * D;
    // --- the big ones (64 MB, fp16) ---
    f16* Apos = (f16*)alloc((size_t)N * N * 2);
    f16* Aneg = (f16*)alloc((size_t)N * N * 2);

    // --- split inputs/weights to bf16 hi/lo (RTN) + workspace init (y==5) ---
    SplitArgs sa;
    sa.d[0] = { eps,   eh,  el,  N * D };
    sa.d[1] = { y_pos, yh,  yl,  N * D };
    sa.d[2] = { W_in,  wih, wil, H * D };
    sa.d[3] = { W_blk, wbh, wbl, 4 * H * H };
    sa.d[4] = { W_out, woh, wol, D * H };
    split_multi<<<dim3(1024, 6), 256, 0, stream>>>(sa, acc, sp, sn, nx, ny);

    // --- generator (MFMA, act hi/lo x W-RTN, 64x64 blocks) ---
    dim3 gh(H / 64, N / 64);
    gen_gemm<<<gh, 128, 0, stream>>>(eh, el, wih, b_in,
                                     nullptr, x0h, x0l, N, H, D, 0, 0);
    gen_gemm<<<gh, 128, 0, stream>>>(x0h, x0l, wbh + 0 * H * H,
                                     b_blk + 0 * H, nullptr, x1h, x1l, N, H, H, 1, 0);
    gen_gemm<<<gh, 128, 0, stream>>>(x1h, x1l, wbh + 1 * H * H,
                                     b_blk + 1 * H, nullptr, x0h, x0l, N, H, H, 1, 0);
    gen_gemm<<<gh, 128, 0, stream>>>(x0h, x0l, wbh + 2 * H * H,
                                     b_blk + 2 * H, nullptr, x1h, x1l, N, H, H, 1, 0);
    gen_gemm<<<gh, 128, 0, stream>>>(x1h, x1l, wbh + 3 * H * H,
                                     b_blk + 3 * H, nullptr, x0h, x0l, N, H, H, 1, 0);
    gen_gemm<<<dim3(D / 64, N / 64), 128, 0, stream>>>(x0h, x0l, woh, b_out,
                                     xo, xh, xl, N, D, H, 0, 1);

    // --- RTN transposes + fused row norms ---
    transpose_rtn<<<dim3(N / 32, D / 32, 2), 256, 0, stream>>>(
        xo, y_pos, xth, yth, nx, ny);

    // --- distance matrices (fp16, single-bf16 MFMA) + fused stats ---
    dist_fused<<<dim3(N / 128, N / 128, 2), 256, 0, stream>>>(
        xh, yh, nx, ny, Apos, Aneg,
        prm_p, prs_p, pcm_p, pcs_p, prm_n, prs_n);

    // --- combine partials into m_row/isr, m_col/isc (parallel) ---
    stats_combine<<<192, 256, 0, stream>>>(prm_p, prs_p, prm_n, prs_n,
                                           pcm_p, pcs_p,
                                           m_row, isr, m_col, isc);

    // --- P@V via MFMA (P built on the fly; sp/sn fp32 via atomics) ---
    pv_mfma<<<dim3(N / 64, KSPLIT, 2), 256, 0, stream>>>(Apos, Aneg,
        yth, xth, m_row, isr, m_col, isc, u_part, w_part, sp, sn);

    // --- combine partials, V^2 reduction ---
    final_reduce<<<(N * D) / 256, 256, 0, stream>>>(u_part, w_part, sp, sn, acc);
    finalize<<<1, 1, 0, stream>>>(acc, out);
}

// Round 19
// 312.839 us; speedup vs baseline: 1.1066x; 1.0434x over previous
//
#include <hip/hip_runtime.h>
#include <math.h>

#define N 4096
#define D 128
#define H 512
#define INV_T 5.0f
#define KSPLIT 4

typedef short bf16x8 __attribute__((ext_vector_type(8)));
typedef float f32x4 __attribute__((ext_vector_type(4)));
typedef unsigned short u16x8 __attribute__((ext_vector_type(8)));
typedef unsigned short u16;
typedef _Float16 f16;
typedef _Float16 f16x4 __attribute__((ext_vector_type(4)));

#define MFMA(a, b, c) __builtin_amdgcn_mfma_f32_16x16x32_bf16((a), (b), (c), 0, 0, 0)

__device__ __forceinline__ float bf2f(u16 h)
{
    return __uint_as_float(((unsigned)h) << 16);
}

// Round-to-nearest bf16 (unbiased) — for operands whose hi is used ALONE.
__device__ __forceinline__ u16 rtn_bf16(float v)
{
    unsigned u = __float_as_uint(v);
    return (u16)((u + 0x7FFFu + ((u >> 16) & 1u)) >> 16);
}

// RTN split (hi usable alone; lo compensates). Cold paths + last gen layer.
__device__ __forceinline__ void split1(float v, u16& h, u16& l)
{
    u16 hh = rtn_bf16(v);
    float r = v - bf2f(hh);
    h = hh;
    l = rtn_bf16(r);
}

// Cheap truncation split (3 ops); hi+lo pair accuracy identical.
__device__ __forceinline__ void split1_trunc(float v, u16& h, u16& l)
{
    unsigned bv = __float_as_uint(v);
    unsigned hb = bv & 0xFFFF0000u;
    float r = v - __uint_as_float(hb);
    h = (u16)(hb >> 16);
    l = (u16)(__float_as_uint(r) >> 16);
}

// ---------------------------------------------------------------------------
// One-shot splitter for 5 flat fp32 arrays -> bf16 hi/lo (RTN, cold) and,
// on the y==5 plane, workspace init (acc/sp/sn/nx/ny).
// ---------------------------------------------------------------------------
struct SplitDesc { const float* src; u16* h; u16* l; int n; };
struct SplitArgs { SplitDesc d[5]; };

__global__ __launch_bounds__(256) void split_multi(SplitArgs args,
    double* acc, float* sp, float* sn, float* nx, float* ny)
{
    if (blockIdx.y == 5) {
        int idx = blockIdx.x * 256 + threadIdx.x;
        if (idx == 0) *acc = 0.0;
        if (idx < N) { sp[idx] = 0.f; sn[idx] = 0.f; nx[idx] = 0.f; ny[idx] = 0.f; }
        return;
    }
    SplitDesc de = args.d[blockIdx.y];
    int idx = (blockIdx.x * 256 + threadIdx.x) * 4;
    if (idx >= de.n) return;
    float4 v = *(const float4*)(de.src + idx);
    ushort4 hv, lv;
    split1(v.x, hv.x, lv.x); split1(v.y, hv.y, lv.y);
    split1(v.z, hv.z, lv.z); split1(v.w, hv.w, lv.w);
    *(ushort4*)(de.h + idx) = hv;
    *(ushort4*)(de.l + idx) = lv;
}

// ---------------------------------------------------------------------------
// Transpose + RTN-bf16 + fused row-norm partials (atomicAdd into nx/ny).
// ---------------------------------------------------------------------------
__global__ __launch_bounds__(256) void transpose_rtn(
    const float* __restrict__ X, const float* __restrict__ Y,
    u16* __restrict__ Xth, u16* __restrict__ Yth,
    float* __restrict__ nx, float* __restrict__ ny)
{
    const float* src = blockIdx.z ? Y : X;
    u16* th = blockIdx.z ? Yth : Xth;
    float* nrm = blockIdx.z ? ny : nx;
    __shared__ float tile[32][33];
    const int t = threadIdx.x;
    const int r0 = blockIdx.x * 32, c0 = blockIdx.y * 32;
    {
        int rit = t >> 3, coff = (t & 7) * 4;
        float4 v = *(const float4*)(src + (size_t)(r0 + rit) * D + c0 + coff);
        tile[rit][coff + 0] = v.x; tile[rit][coff + 1] = v.y;
        tile[rit][coff + 2] = v.z; tile[rit][coff + 3] = v.w;
        float sq = v.x * v.x + v.y * v.y + v.z * v.z + v.w * v.w;
        sq += __shfl_xor(sq, 1);
        sq += __shfl_xor(sq, 2);
        sq += __shfl_xor(sq, 4);
        if ((t & 7) == 0) atomicAdd(&nrm[r0 + rit], sq);
    }
    __syncthreads();
    {
        int cit = t >> 3, roff = (t & 7) * 4;
        ushort4 hv;
        hv.x = rtn_bf16(tile[roff + 0][cit]);
        hv.y = rtn_bf16(tile[roff + 1][cit]);
        hv.z = rtn_bf16(tile[roff + 2][cit]);
        hv.w = rtn_bf16(tile[roff + 3][cit]);
        *(ushort4*)(th + (size_t)(c0 + cit) * N + r0 + roff) = hv;
    }
}

// ---------------------------------------------------------------------------
// Generator GEMM: A = activations hi/lo bf16 pair, B = weights single RTN
// bf16. Tile 64x64, BK=64 (halved barrier count vs BK=32 — chain is
// barrier/latency-bound at 2 blocks/CU), 128 threads (2 waves x 32 rows,
// proven micro-shape per k-half). rtn_out=1 on the last layer only.
// ---------------------------------------------------------------------------
__global__ __launch_bounds__(128) void gen_gemm(
    const u16* __restrict__ Ah, const u16* __restrict__ Al,
    const u16* __restrict__ Bh,
    const float* __restrict__ bias,
    float* __restrict__ C, u16* __restrict__ Ch, u16* __restrict__ Cl,
    int M, int Nn, int K, int resid, int rtn_out)
{
    __shared__ u16 AhS[64][72], AlS[64][72];
    __shared__ u16 BhS[64][72];
    const int t = threadIdx.x;
    const int w = t >> 6, lane = t & 63;
    const int quad = lane >> 4, l16 = lane & 15;
    const int bm = blockIdx.y * 64, bn = blockIdx.x * 64;
    f32x4 acc[2][4] = {};

    for (int k0 = 0; k0 < K; k0 += 64) {
        __syncthreads();
        #pragma unroll
        for (int p = 0; p < 4; ++p) {
            int slot = t + p * 128;          // 512 slots = 64 rows x 8 k-octets
            int row = slot >> 3, koff = (slot & 7) << 3;
            size_t ga = (size_t)(bm + row) * K + k0 + koff;
            size_t gb = (size_t)(bn + row) * K + k0 + koff;
            *(u16x8*)&AhS[row][koff] = *(const u16x8*)(Ah + ga);
            *(u16x8*)&AlS[row][koff] = *(const u16x8*)(Al + ga);
            *(u16x8*)&BhS[row][koff] = *(const u16x8*)(Bh + gb);
        }
        __syncthreads();
        #pragma unroll
        for (int kh = 0; kh < 2; ++kh) {
            const int kk = kh * 32 + quad * 8;
            bf16x8 af[2], alf[2], bhf[4];
            #pragma unroll
            for (int mi = 0; mi < 2; ++mi) {
                int r = w * 32 + mi * 16 + l16;
                af[mi]  = *(const bf16x8*)&AhS[r][kk];
                alf[mi] = *(const bf16x8*)&AlS[r][kk];
            }
            #pragma unroll
            for (int ni = 0; ni < 4; ++ni)
                bhf[ni] = *(const bf16x8*)&BhS[ni * 16 + l16][kk];
            #pragma unroll
            for (int mi = 0; mi < 2; ++mi)
                #pragma unroll
                for (int ni = 0; ni < 4; ++ni) {
                    acc[mi][ni] = MFMA(af[mi], bhf[ni], acc[mi][ni]);
                    acc[mi][ni] = MFMA(alf[mi], bhf[ni], acc[mi][ni]);
                }
        }
    }
    #pragma unroll
    for (int mi = 0; mi < 2; ++mi)
        #pragma unroll
        for (int ni = 0; ni < 4; ++ni)
            #pragma unroll
            for (int r = 0; r < 4; ++r) {
                int gm = bm + w * 32 + mi * 16 + quad * 4 + r;
                int gn = bn + ni * 16 + l16;
                float v = acc[mi][ni][r] + bias[gn];
                if (resid) {
                    size_t o2 = (size_t)gm * K + gn;
                    float prev = bf2f(Ah[o2]) + bf2f(Al[o2]);
                    v = prev + fmaxf(v, 0.0f);
                }
                size_t o = (size_t)gm * Nn + gn;
                if (C) C[o] = v;
                u16 hh, ll;
                if (rtn_out) split1(v, hh, ll);
                else         split1_trunc(v, hh, ll);
                Ch[o] = hh; Cl[o] = ll;
            }
}

// ---------------------------------------------------------------------------
// Distance via SINGLE RTN-bf16 MFMA, fused stats, pos+neg merged. A fp16.
// B-operand column permutation (proven): fragment slot (ni,l16) holds
// j = l16*4+ni -> one f16x4 store per (mi,r), ny as one float4 load.
// ---------------------------------------------------------------------------
__global__ __launch_bounds__(256) void dist_fused(
    const u16* __restrict__ Xh, const u16* __restrict__ Yh,
    const float* __restrict__ nx, const float* __restrict__ ny,
    f16* __restrict__ Apos, f16* __restrict__ Aneg,
    float* __restrict__ prm_p, float* __restrict__ prs_p,
    float* __restrict__ pcm_p, float* __restrict__ pcs_p,
    float* __restrict__ prm_n, float* __restrict__ prs_n)
{
    const int mat = blockIdx.z;                // 0: X vs Y ; 1: X vs X
    const u16* Bhp = mat ? Xh : Yh;
    const float* nb = mat ? nx : ny;
    f16* Out = mat ? Aneg : Apos;
    float* prm = mat ? prm_n : prm_p;
    float* prs = mat ? prs_n : prs_p;

    __shared__ u16 XhS[128][40], YhS[128][40];
    const int t = threadIdx.x;
    const int w = t >> 6, lane = t & 63;
    const int quad = lane >> 4, l16 = lane & 15;
    const int wm = w & 1, wn = w >> 1;
    const int bm = blockIdx.y * 128, bn = blockIdx.x * 128;
    f32x4 acc[4][4] = {};

    for (int k0 = 0; k0 < D; k0 += 32) {
        __syncthreads();
        #pragma unroll
        for (int p = 0; p < 2; ++p) {
            int slot = t + p * 256;            // 512 slots = 128 rows x 4 octets
            int row = slot >> 2, koff = (slot & 3) << 3;
            *(u16x8*)&XhS[row][koff] =
                *(const u16x8*)(Xh + (size_t)(bm + row) * D + k0 + koff);
            int pr = ((row & 3) << 4) | ((row & 63) >> 2) | (row & 64);
            int kf = koff ^ (((pr >> 4) & 3) << 3);
            *(u16x8*)&YhS[pr][kf] =
                *(const u16x8*)(Bhp + (size_t)(bn + row) * D + k0 + koff);
        }
        __syncthreads();
        bf16x8 af[4], bhf[4];
        #pragma unroll
        for (int mi = 0; mi < 4; ++mi)
            af[mi] = *(const bf16x8*)&XhS[wm * 64 + mi * 16 + l16][quad * 8];
        #pragma unroll
        for (int ni = 0; ni < 4; ++ni)
            bhf[ni] = *(const bf16x8*)
                &YhS[wn * 64 + ni * 16 + l16][(quad * 8) ^ ((ni & 3) << 3)];
        #pragma unroll
        for (int mi = 0; mi < 4; ++mi)
            #pragma unroll
            for (int ni = 0; ni < 4; ++ni)
                acc[mi][ni] = MFMA(af[mi], bhf[ni], acc[mi][ni]);
    }
    // lane's 4 j's are contiguous: jb..jb+3
    const int jb = bn + wn * 64 + (l16 << 2);
    const float4 nyv = *(const float4*)(nb + jb);
    const float nyl[4] = {nyv.x, nyv.y, nyv.z, nyv.w};
    // --- transform in place + vector store ---
    #pragma unroll
    for (int mi = 0; mi < 4; ++mi)
        #pragma unroll
        for (int r = 0; r < 4; ++r) {
            int gm = bm + wm * 64 + mi * 16 + quad * 4 + r;
            float nxm = nx[gm];
            f16x4 ov;
            #pragma unroll
            for (int ni = 0; ni < 4; ++ni) {
                float d2 = nxm + nyl[ni] - 2.0f * acc[mi][ni][r];
                float a = -sqrtf(fmaxf(d2, 0.0f)) * INV_T;
                if (mat && gm == jb + ni) a = -5.0e6f;
                acc[mi][ni][r] = a;
                ov[ni] = (f16)a;
            }
            *(f16x4*)(Out + (size_t)gm * N + jb) = ov;
        }
    // --- row partials: per (mi,r), reduce over ni (in-lane) + l16 (shfl) ---
    const int ct = blockIdx.x * 2 + wn;
    #pragma unroll
    for (int mi = 0; mi < 4; ++mi)
        #pragma unroll
        for (int r = 0; r < 4; ++r) {
            float m = fmaxf(fmaxf(acc[mi][0][r], acc[mi][1][r]),
                            fmaxf(acc[mi][2][r], acc[mi][3][r]));
            m = fmaxf(m, __shfl_xor(m, 1));
            m = fmaxf(m, __shfl_xor(m, 2));
            m = fmaxf(m, __shfl_xor(m, 4));
            m = fmaxf(m, __shfl_xor(m, 8));
            float s = __expf(acc[mi][0][r] - m) + __expf(acc[mi][1][r] - m)
                    + __expf(acc[mi][2][r] - m) + __expf(acc[mi][3][r] - m);
            s += __shfl_xor(s, 1); s += __shfl_xor(s, 2);
            s += __shfl_xor(s, 4); s += __shfl_xor(s, 8);
            if (l16 == 0) {
                int grow = bm + wm * 64 + mi * 16 + quad * 4 + r;
                prm[(size_t)ct * N + grow] = m;
                prs[(size_t)ct * N + grow] = s;
            }
        }
    // --- col partials (pos only): per ni, in-lane over (mi,r) + quad shfl ---
    if (mat == 0) {
        const int rt = blockIdx.y * 2 + wm;
        #pragma unroll
        for (int ni = 0; ni < 4; ++ni) {
            float m = -3.0e38f;
            #pragma unroll
            for (int mi = 0; mi < 4; ++mi)
                #pragma unroll
                for (int r = 0; r < 4; ++r)
                    m = fmaxf(m, acc[mi][ni][r]);
            m = fmaxf(m, __shfl_xor(m, 16));
            m = fmaxf(m, __shfl_xor(m, 32));
            float s = 0.f;
            #pragma unroll
            for (int mi = 0; mi < 4; ++mi)
                #pragma unroll
                for (int r = 0; r < 4; ++r)
                    s += __expf(acc[mi][ni][r] - m);
            s += __shfl_xor(s, 16);
            s += __shfl_xor(s, 32);
            if (quad == 0) {
                pcm_p[(size_t)rt * N + jb + ni] = m;
                pcs_p[(size_t)rt * N + jb + ni] = s;
            }
        }
    }
}

// ---------------------------------------------------------------------------
// Combine partials into row/col softmax stats — parallel (192 x 256).
// ---------------------------------------------------------------------------
__global__ __launch_bounds__(256) void stats_combine(
    const float* __restrict__ prm_p, const float* __restrict__ prs_p,
    const float* __restrict__ prm_n, const float* __restrict__ prs_n,
    const float* __restrict__ pcm_p, const float* __restrict__ pcs_p,
    float* __restrict__ m_row, float* __restrict__ isr,
    float* __restrict__ m_col, float* __restrict__ isc)
{
    __shared__ float Ms[4][64], Ss[4][64];
    const int t = threadIdx.x;
    const int g = t >> 6, l = t & 63;
    const int idx = blockIdx.x * 64 + l;
    const int c0 = g * 16;

    float m = -3.0e38f, s = 0.f;
    if (idx < N) {
        const int i = idx;
        #pragma unroll 4
        for (int c = c0; c < c0 + 16; ++c) {
            m = fmaxf(m, prm_p[(size_t)c * N + i]);
            m = fmaxf(m, prm_n[(size_t)c * N + i]);
        }
        #pragma unroll 4
        for (int c = c0; c < c0 + 16; ++c) {
            s += prs_p[(size_t)c * N + i] * __expf(prm_p[(size_t)c * N + i] - m);
            s += prs_n[(size_t)c * N + i] * __expf(prm_n[(size_t)c * N + i] - m);
        }
    } else {
        const int mat = (idx - N) >> 12;
        const int j = idx & (N - 1);
        const float* pm = mat ? prm_n : pcm_p;
        const float* ps = mat ? prs_n : pcs_p;
        #pragma unroll 4
        for (int c = c0; c < c0 + 16; ++c)
            m = fmaxf(m, pm[(size_t)c * N + j]);
        #pragma unroll 4
        for (int c = c0; c < c0 + 16; ++c)
            s += ps[(size_t)c * N + j] * __expf(pm[(size_t)c * N + j] - m);
    }
    Ms[g][l] = m; Ss[g][l] = s;
    __syncthreads();
    if (g == 0) {
        float m0 = Ms[0][l], m1 = Ms[1][l], m2 = Ms[2][l], m3 = Ms[3][l];
        float mm = fmaxf(fmaxf(m0, m1), fmaxf(m2, m3));
        float ss = Ss[0][l] * __expf(m0 - mm) + Ss[1][l] * __expf(m1 - mm)
                 + Ss[2][l] * __expf(m2 - mm) + Ss[3][l] * __expf(m3 - mm);
        if (idx < N) {
            m_row[idx] = mm;
            isr[idx] = 1.0f / sqrtf(ss);
        } else {
            const int mat = (idx - N) >> 12;
            const int j = idx & (N - 1);
            m_col[mat * N + j] = mm;
            isc[mat * N + j] = 1.0f / sqrtf(ss);
        }
    }
}

// ---------------------------------------------------------------------------
// pv via MFMA (proven form): A fp16 tile -> P (fp32 rowsums -> sp/sn),
// split P (trunc) to bf16 hi/lo in LDS, MFMA P @ B (B = RTN-bf16 transposed
// [d][j], hi only). Unpermuted staging; scalar C-stores (lane-coalesced).
// ---------------------------------------------------------------------------
__global__ __launch_bounds__(256) void pv_mfma(
    const f16* __restrict__ Apos, const f16* __restrict__ Aneg,
    const u16* __restrict__ Yth, const u16* __restrict__ Xth,
    const float* __restrict__ m_row, const float* __restrict__ isr,
    const float* __restrict__ m_col, const float* __restrict__ isc,
    float* __restrict__ u_part, float* __restrict__ w_part,
    float* __restrict__ sp_arr, float* __restrict__ sn_arr)
{
    const int mat = blockIdx.z;
    const f16* Am = mat ? Aneg : Apos;
    const u16* Bh = mat ? Xth : Yth;
    const float* mc = m_col + mat * N;
    const float* ic = isc + mat * N;
    float* Cp = (mat ? w_part : u_part) + (size_t)blockIdx.y * (N * D);
    float* spn = mat ? sn_arr : sp_arr;

    __shared__ u16 BhS[128][72];
    __shared__ u16 PhS[64][72], PlS[64][72];
    __shared__ float mrS[64], isrS[64];

    const int t = threadIdx.x;
    const int w = t >> 6, lane = t & 63;
    const int quad = lane >> 4, l16 = lane & 15;
    const int bm = blockIdx.x * 64;
    const int jbase = blockIdx.y * (N / KSPLIT);
    const int arow = t >> 4;          // 0..15
    const int aj = (t & 15) << 2;     // 0..60

    if (t < 64) { mrS[t] = m_row[bm + t]; isrS[t] = isr[bm + t]; }

    f32x4 acc[8] = {};
    float rs[4] = {0.f, 0.f, 0.f, 0.f};

    for (int jt = 0; jt < (N / KSPLIT) / 64; ++jt) {
        const int j0 = jbase + jt * 64;
        __syncthreads();   // protect previous iteration's LDS reads (+ mrS init)
        #pragma unroll
        for (int p = 0; p < 4; ++p) {
            int slot = t + p * 256;
            int d = slot >> 3, joff = (slot & 7) << 3;
            *(u16x8*)&BhS[d][joff] = *(const u16x8*)(Bh + (size_t)d * N + j0 + joff);
        }
        float4 mcv = *(const float4*)(mc + j0 + aj);
        float4 icv = *(const float4*)(ic + j0 + aj);
        #pragma unroll
        for (int s = 0; s < 4; ++s) {
            int row = arow + s * 16;
            f16x4 av = *(const f16x4*)(Am + (size_t)(bm + row) * N + j0 + aj);
            float mr = mrS[row], sr = isrS[row];
            float p0 = __expf((float)av.x - 0.5f * (mr + mcv.x)) * (sr * icv.x);
            float p1 = __expf((float)av.y - 0.5f * (mr + mcv.y)) * (sr * icv.y);
            float p2 = __expf((float)av.z - 0.5f * (mr + mcv.z)) * (sr * icv.z);
            float p3 = __expf((float)av.w - 0.5f * (mr + mcv.w)) * (sr * icv.w);
            rs[s] += p0 + p1 + p2 + p3;
            ushort4 hv, lv;
            split1_trunc(p0, hv.x, lv.x); split1_trunc(p1, hv.y, lv.y);
            split1_trunc(p2, hv.z, lv.z); split1_trunc(p3, hv.w, lv.w);
            *(ushort4*)&PhS[row][aj] = hv;
            *(ushort4*)&PlS[row][aj] = lv;
        }
        __syncthreads();
        #pragma unroll
        for (int ks = 0; ks < 2; ++ks) {
            const int kk = ks * 32 + quad * 8;
            bf16x8 ph = *(const bf16x8*)&PhS[w * 16 + l16][kk];
            bf16x8 pl = *(const bf16x8*)&PlS[w * 16 + l16][kk];
            #pragma unroll
            for (int ni = 0; ni < 8; ++ni) {
                bf16x8 bh = *(const bf16x8*)&BhS[ni * 16 + l16][kk];
                acc[ni] = MFMA(ph, bh, acc[ni]);
                acc[ni] = MFMA(pl, bh, acc[ni]);
            }
        }
    }
    #pragma unroll
    for (int ni = 0; ni < 8; ++ni)
        #pragma unroll
        for (int r = 0; r < 4; ++r) {
            int row = w * 16 + quad * 4 + r;
            int col = ni * 16 + l16;
            Cp[(size_t)(bm + row) * D + col] = acc[ni][r];
        }
    #pragma unroll
    for (int s = 0; s < 4; ++s) {
        float v = rs[s];
        v += __shfl_xor(v, 1); v += __shfl_xor(v, 2);
        v += __shfl_xor(v, 4); v += __shfl_xor(v, 8);
        if (l16 == 0) atomicAdd(&spn[bm + arow + s * 16], v);
    }
}

// ---------------------------------------------------------------------------
// Sum split-K partials, V = sn*u - sp*sn*w, accumulate sum(V^2).
// ---------------------------------------------------------------------------
__global__ __launch_bounds__(256) void final_reduce(const float* __restrict__ u_part,
    const float* __restrict__ w_part, const float* __restrict__ sp_arr,
    const float* __restrict__ sn_arr, double* __restrict__ acc_out)
{
    __shared__ float red[256];
    const int t = threadIdx.x;
    const int idx = blockIdx.x * 256 + t;
    float u = 0.f, w = 0.f;
    #pragma unroll
    for (int c = 0; c < KSPLIT; ++c) {
        u += u_part[(size_t)c * (N * D) + idx];
        w += w_part[(size_t)c * (N * D) + idx];
    }
    const int i = idx >> 7;
    const float sn = sn_arr[i];
    const float v = sn * u - sp_arr[i] * sn * w;
    red[t] = v * v; __syncthreads();
    for (int s = 128; s > 0; s >>= 1) { if (t < s) red[t] += red[t + s]; __syncthreads(); }
    if (!t) atomicAdd(acc_out, (double)red[0]);
}

__global__ void finalize(const double* __restrict__ acc, float* __restrict__ out)
{
    out[0] = (float)(*acc * (1.0 / ((double)N * (double)D)));
}

// ---------------------------------------------------------------------------
extern "C" void kernel_launch(void* const* d_in, const int* in_sizes, int n_in,
                              void* d_out, int out_size, void* d_ws, size_t ws_size,
                              hipStream_t stream)
{
    const float* y_pos = (const float*)d_in[0];
    const float* eps   = (const float*)d_in[1];
    const float* W_in  = (const float*)d_in[2];
    const float* b_in  = (const float*)d_in[3];
    const float* W_blk = (const float*)d_in[4];
    const float* b_blk = (const float*)d_in[5];
    const float* W_out = (const float*)d_in[6];
    const float* b_out = (const float*)d_in[7];
    float* out = (float*)d_out;
    (void)in_sizes; (void)n_in; (void)out_size; (void)ws_size;

    char* p = (char*)d_ws;
    auto alloc = [&](size_t bytes) {
        char* r = p;
        p += (bytes + 255) & ~(size_t)255;
        return r;
    };
    // --- small arrays ---
    double* acc  = (double*)alloc(8);
    float* sp     = (float*)alloc(N * 4);
    float* sn     = (float*)alloc(N * 4);
    float* m_row  = (float*)alloc(N * 4);
    float* isr    = (float*)alloc(N * 4);
    float* m_col  = (float*)alloc(2 * N * 4);
    float* isc    = (float*)alloc(2 * N * 4);
    float* nx     = (float*)alloc(N * 4);
    float* ny     = (float*)alloc(N * 4);
    // --- eh/el (2 MB; only live through the first gen layer) ---
    u16* eh = (u16*)alloc((size_t)N * D * 2);
    u16* el = (u16*)alloc((size_t)N * D * 2);
    // --- xo fp32 + bf16 x/y arrays ---
    float* xo  = (float*)alloc((size_t)N * D * 4);
    u16* xh    = (u16*)alloc((size_t)N * D * 2);
    u16* xl    = (u16*)alloc((size_t)N * D * 2);
    u16* xth   = (u16*)alloc((size_t)N * D * 2);
    u16* yh    = (u16*)alloc((size_t)N * D * 2);
    u16* yl    = (u16*)alloc((size_t)N * D * 2);
    u16* yth   = (u16*)alloc((size_t)N * D * 2);
    // --- generator region (21 MB): activations + weights; later aliased by
    //     stats partials (6 MB) then u/w_part (16 MB) ---
    char* genreg = alloc((size_t)(4 * (size_t)N * H * 2
                                + 2 * (size_t)H * D * 2
                                + 2 * (size_t)4 * H * H * 2
                                + 2 * (size_t)D * H * 2));
    u16* x0h = (u16*)genreg;
    u16* x0l = x0h + (size_t)N * H;
    u16* x1h = x0l + (size_t)N * H;
    u16* x1l = x1h + (size_t)N * H;
    u16* wih = x1l + (size_t)N * H;
    u16* wil = wih + (size_t)H * D;
    u16* wbh = wil + (size_t)H * D;
    u16* wbl = wbh + (size_t)4 * H * H;
    u16* woh = wbl + (size_t)4 * H * H;
    u16* wol = woh + (size_t)D * H;
    // aliases (disjoint lifetimes, stream-ordered):
    float* prm_p = (float*)genreg;                 // 64*N each = 1 MB
    float* prs_p = prm_p + 64 * N;
    float* prm_n = prs_p + 64 * N;
    float* prs_n = prm_n + 64 * N;
    float* pcm_p = prs_n + 64 * N;
    float* pcs_p = pcm_p + 64 * N;                 // ends at 6 MB
    float* u_part = (float*)genreg;                // KSPLIT*N*D = 8 MB
    float* w_part = u_part + (size_t)KSPLIT * N * D;
    // --- the big ones (64 MB, fp16) ---
    f16* Apos = (f16*)alloc((size_t)N * N * 2);
    f16* Aneg = (f16*)alloc((size_t)N * N * 2);

    // --- split inputs/weights to bf16 hi/lo (RTN) + workspace init (y==5) ---
    SplitArgs sa;
    sa.d[0] = { eps,   eh,  el,  N * D };
    sa.d[1] = { y_pos, yh,  yl,  N * D };
    sa.d[2] = { W_in,  wih, wil, H * D };
    sa.d[3] = { W_blk, wbh, wbl, 4 * H * H };
    sa.d[4] = { W_out, woh, wol, D * H };
    split_multi<<<dim3(1024, 6), 256, 0, stream>>>(sa, acc, sp, sn, nx, ny);

    // --- generator (MFMA, act hi/lo x W-RTN, 64x64 blocks, BK=64) ---
    dim3 gh(H / 64, N / 64);
    gen_gemm<<<gh, 128, 0, stream>>>(eh, el, wih, b_in,
                                     nullptr, x0h, x0l, N, H, D, 0, 0);
    gen_gemm<<<gh, 128, 0, stream>>>(x0h, x0l, wbh + 0 * H * H,
                                     b_blk + 0 * H, nullptr, x1h, x1l, N, H, H, 1, 0);
    gen_gemm<<<gh, 128, 0, stream>>>(x1h, x1l, wbh + 1 * H * H,
                                     b_blk + 1 * H, nullptr, x0h, x0l, N, H, H, 1, 0);
    gen_gemm<<<gh, 128, 0, stream>>>(x0h, x0l, wbh + 2 * H * H,
                                     b_blk + 2 * H, nullptr, x1h, x1l, N, H, H, 1, 0);
    gen_gemm<<<gh, 128, 0, stream>>>(x1h, x1l, wbh + 3 * H * H,
                                     b_blk + 3 * H, nullptr, x0h, x0l, N, H, H, 1, 0);
    gen_gemm<<<dim3(D / 64, N / 64), 128, 0, stream>>>(x0h, x0l, woh, b_out,
                                     xo, xh, xl, N, D, H, 0, 1);

    // --- RTN transposes + fused row norms ---
    transpose_rtn<<<dim3(N / 32, D / 32, 2), 256, 0, stream>>>(
        xo, y_pos, xth, yth, nx, ny);

    // --- distance matrices (fp16, single-bf16 MFMA) + fused stats ---
    dist_fused<<<dim3(N / 128, N / 128, 2), 256, 0, stream>>>(
        xh, yh, nx, ny, Apos, Aneg,
        prm_p, prs_p, pcm_p, pcs_p, prm_n, prs_n);

    // --- combine partials into m_row/isr, m_col/isc (parallel) ---
    stats_combine<<<192, 256, 0, stream>>>(prm_p, prs_p, prm_n, prs_n,
                                           pcm_p, pcs_p,
                                           m_row, isr, m_col, isc);

    // --- P@V via MFMA (P built on the fly; sp/sn fp32 via atomics) ---
    pv_mfma<<<dim3(N / 64, KSPLIT, 2), 256, 0, stream>>>(Apos, Aneg,
        yth, xth, m_row, isr, m_col, isc, u_part, w_part, sp, sn);

    // --- combine partials, V^2 reduction ---
    final_reduce<<<(N * D) / 256, 256, 0, stream>>>(u_part, w_part, sp, sn, acc);
    finalize<<<1, 1, 0, stream>>>(acc, out);
}

// Round 20
// 310.817 us; speedup vs baseline: 1.1139x; 1.0065x over previous
//
#include <hip/hip_runtime.h>
#include <math.h>

#define N 4096
#define D 128
#define H 512
#define INV_T 5.0f
#define KSPLIT 4

typedef short bf16x8 __attribute__((ext_vector_type(8)));
typedef float f32x4 __attribute__((ext_vector_type(4)));
typedef unsigned short u16x8 __attribute__((ext_vector_type(8)));
typedef unsigned short u16;
typedef _Float16 f16;
typedef _Float16 f16x4 __attribute__((ext_vector_type(4)));

#define MFMA(a, b, c) __builtin_amdgcn_mfma_f32_16x16x32_bf16((a), (b), (c), 0, 0, 0)

__device__ __forceinline__ float bf2f(u16 h)
{
    return __uint_as_float(((unsigned)h) << 16);
}

// Round-to-nearest bf16 (unbiased) — for operands whose hi is used ALONE.
__device__ __forceinline__ u16 rtn_bf16(float v)
{
    unsigned u = __float_as_uint(v);
    return (u16)((u + 0x7FFFu + ((u >> 16) & 1u)) >> 16);
}

// RTN split (hi usable alone; lo compensates). Cold paths + last gen layer.
__device__ __forceinline__ void split1(float v, u16& h, u16& l)
{
    u16 hh = rtn_bf16(v);
    float r = v - bf2f(hh);
    h = hh;
    l = rtn_bf16(r);
}

// Cheap truncation split (3 ops); hi+lo pair accuracy identical.
__device__ __forceinline__ void split1_trunc(float v, u16& h, u16& l)
{
    unsigned bv = __float_as_uint(v);
    unsigned hb = bv & 0xFFFF0000u;
    float r = v - __uint_as_float(hb);
    h = (u16)(hb >> 16);
    l = (u16)(__float_as_uint(r) >> 16);
}

// ---------------------------------------------------------------------------
// One-shot splitter for 5 flat fp32 arrays -> bf16 hi/lo (RTN, cold) and,
// on the y==5 plane, workspace init (acc/sp/sn/nx/ny).
// ---------------------------------------------------------------------------
struct SplitDesc { const float* src; u16* h; u16* l; int n; };
struct SplitArgs { SplitDesc d[5]; };

__global__ __launch_bounds__(256) void split_multi(SplitArgs args,
    double* acc, float* sp, float* sn, float* nx, float* ny)
{
    if (blockIdx.y == 5) {
        int idx = blockIdx.x * 256 + threadIdx.x;
        if (idx == 0) *acc = 0.0;
        if (idx < N) { sp[idx] = 0.f; sn[idx] = 0.f; nx[idx] = 0.f; ny[idx] = 0.f; }
        return;
    }
    SplitDesc de = args.d[blockIdx.y];
    int idx = (blockIdx.x * 256 + threadIdx.x) * 4;
    if (idx >= de.n) return;
    float4 v = *(const float4*)(de.src + idx);
    ushort4 hv, lv;
    split1(v.x, hv.x, lv.x); split1(v.y, hv.y, lv.y);
    split1(v.z, hv.z, lv.z); split1(v.w, hv.w, lv.w);
    *(ushort4*)(de.h + idx) = hv;
    *(ushort4*)(de.l + idx) = lv;
}

// ---------------------------------------------------------------------------
// Transpose + RTN-bf16 + fused row-norm partials (atomicAdd into nx/ny).
// ---------------------------------------------------------------------------
__global__ __launch_bounds__(256) void transpose_rtn(
    const float* __restrict__ X, const float* __restrict__ Y,
    u16* __restrict__ Xth, u16* __restrict__ Yth,
    float* __restrict__ nx, float* __restrict__ ny)
{
    const float* src = blockIdx.z ? Y : X;
    u16* th = blockIdx.z ? Yth : Xth;
    float* nrm = blockIdx.z ? ny : nx;
    __shared__ float tile[32][33];
    const int t = threadIdx.x;
    const int r0 = blockIdx.x * 32, c0 = blockIdx.y * 32;
    {
        int rit = t >> 3, coff = (t & 7) * 4;
        float4 v = *(const float4*)(src + (size_t)(r0 + rit) * D + c0 + coff);
        tile[rit][coff + 0] = v.x; tile[rit][coff + 1] = v.y;
        tile[rit][coff + 2] = v.z; tile[rit][coff + 3] = v.w;
        float sq = v.x * v.x + v.y * v.y + v.z * v.z + v.w * v.w;
        sq += __shfl_xor(sq, 1);
        sq += __shfl_xor(sq, 2);
        sq += __shfl_xor(sq, 4);
        if ((t & 7) == 0) atomicAdd(&nrm[r0 + rit], sq);
    }
    __syncthreads();
    {
        int cit = t >> 3, roff = (t & 7) * 4;
        ushort4 hv;
        hv.x = rtn_bf16(tile[roff + 0][cit]);
        hv.y = rtn_bf16(tile[roff + 1][cit]);
        hv.z = rtn_bf16(tile[roff + 2][cit]);
        hv.w = rtn_bf16(tile[roff + 3][cit]);
        *(ushort4*)(th + (size_t)(c0 + cit) * N + r0 + roff) = hv;
    }
}

// ---------------------------------------------------------------------------
// Generator GEMM: A = activations hi/lo bf16 pair, B = weights single RTN
// bf16. Tile 64x64, BK=128 (4 barriers for K=512, 0 loop barriers for
// K=128 — chain is barrier-drain-bound at grid-capped 2 blocks/CU),
// 128 threads (2 waves x 32 rows, proven micro-shape per k-quarter).
// rtn_out=1 on the last layer only.
// ---------------------------------------------------------------------------
__global__ __launch_bounds__(128) void gen_gemm(
    const u16* __restrict__ Ah, const u16* __restrict__ Al,
    const u16* __restrict__ Bh,
    const float* __restrict__ bias,
    float* __restrict__ C, u16* __restrict__ Ch, u16* __restrict__ Cl,
    int M, int Nn, int K, int resid, int rtn_out)
{
    __shared__ u16 AhS[64][136], AlS[64][136];
    __shared__ u16 BhS[64][136];
    const int t = threadIdx.x;
    const int w = t >> 6, lane = t & 63;
    const int quad = lane >> 4, l16 = lane & 15;
    const int bm = blockIdx.y * 64, bn = blockIdx.x * 64;
    f32x4 acc[2][4] = {};

    for (int k0 = 0; k0 < K; k0 += 128) {
        __syncthreads();
        #pragma unroll
        for (int p = 0; p < 8; ++p) {
            int slot = t + p * 128;          // 1024 slots = 64 rows x 16 k-octets
            int row = slot >> 4, koff = (slot & 15) << 3;
            size_t ga = (size_t)(bm + row) * K + k0 + koff;
            size_t gb = (size_t)(bn + row) * K + k0 + koff;
            *(u16x8*)&AhS[row][koff] = *(const u16x8*)(Ah + ga);
            *(u16x8*)&AlS[row][koff] = *(const u16x8*)(Al + ga);
            *(u16x8*)&BhS[row][koff] = *(const u16x8*)(Bh + gb);
        }
        __syncthreads();
        #pragma unroll
        for (int kh = 0; kh < 4; ++kh) {
            const int kk = kh * 32 + quad * 8;
            bf16x8 af[2], alf[2], bhf[4];
            #pragma unroll
            for (int mi = 0; mi < 2; ++mi) {
                int r = w * 32 + mi * 16 + l16;
                af[mi]  = *(const bf16x8*)&AhS[r][kk];
                alf[mi] = *(const bf16x8*)&AlS[r][kk];
            }
            #pragma unroll
            for (int ni = 0; ni < 4; ++ni)
                bhf[ni] = *(const bf16x8*)&BhS[ni * 16 + l16][kk];
            #pragma unroll
            for (int mi = 0; mi < 2; ++mi)
                #pragma unroll
                for (int ni = 0; ni < 4; ++ni) {
                    acc[mi][ni] = MFMA(af[mi], bhf[ni], acc[mi][ni]);
                    acc[mi][ni] = MFMA(alf[mi], bhf[ni], acc[mi][ni]);
                }
        }
    }
    #pragma unroll
    for (int mi = 0; mi < 2; ++mi)
        #pragma unroll
        for (int ni = 0; ni < 4; ++ni)
            #pragma unroll
            for (int r = 0; r < 4; ++r) {
                int gm = bm + w * 32 + mi * 16 + quad * 4 + r;
                int gn = bn + ni * 16 + l16;
                float v = acc[mi][ni][r] + bias[gn];
                if (resid) {
                    size_t o2 = (size_t)gm * K + gn;
                    float prev = bf2f(Ah[o2]) + bf2f(Al[o2]);
                    v = prev + fmaxf(v, 0.0f);
                }
                size_t o = (size_t)gm * Nn + gn;
                if (C) C[o] = v;
                u16 hh, ll;
                if (rtn_out) split1(v, hh, ll);
                else         split1_trunc(v, hh, ll);
                Ch[o] = hh; Cl[o] = ll;
            }
}

// ---------------------------------------------------------------------------
// Distance via SINGLE RTN-bf16 MFMA, fused stats, pos+neg merged. A fp16.
// B-operand column permutation (proven): fragment slot (ni,l16) holds
// j = l16*4+ni -> one f16x4 store per (mi,r), ny as one float4 load.
// ---------------------------------------------------------------------------
__global__ __launch_bounds__(256) void dist_fused(
    const u16* __restrict__ Xh, const u16* __restrict__ Yh,
    const float* __restrict__ nx, const float* __restrict__ ny,
    f16* __restrict__ Apos, f16* __restrict__ Aneg,
    float* __restrict__ prm_p, float* __restrict__ prs_p,
    float* __restrict__ pcm_p, float* __restrict__ pcs_p,
    float* __restrict__ prm_n, float* __restrict__ prs_n)
{
    const int mat = blockIdx.z;                // 0: X vs Y ; 1: X vs X
    const u16* Bhp = mat ? Xh : Yh;
    const float* nb = mat ? nx : ny;
    f16* Out = mat ? Aneg : Apos;
    float* prm = mat ? prm_n : prm_p;
    float* prs = mat ? prs_n : prs_p;

    __shared__ u16 XhS[128][40], YhS[128][40];
    const int t = threadIdx.x;
    const int w = t >> 6, lane = t & 63;
    const int quad = lane >> 4, l16 = lane & 15;
    const int wm = w & 1, wn = w >> 1;
    const int bm = blockIdx.y * 128, bn = blockIdx.x * 128;
    f32x4 acc[4][4] = {};

    for (int k0 = 0; k0 < D; k0 += 32) {
        __syncthreads();
        #pragma unroll
        for (int p = 0; p < 2; ++p) {
            int slot = t + p * 256;            // 512 slots = 128 rows x 4 octets
            int row = slot >> 2, koff = (slot & 3) << 3;
            *(u16x8*)&XhS[row][koff] =
                *(const u16x8*)(Xh + (size_t)(bm + row) * D + k0 + koff);
            int pr = ((row & 3) << 4) | ((row & 63) >> 2) | (row & 64);
            int kf = koff ^ (((pr >> 4) & 3) << 3);
            *(u16x8*)&YhS[pr][kf] =
                *(const u16x8*)(Bhp + (size_t)(bn + row) * D + k0 + koff);
        }
        __syncthreads();
        bf16x8 af[4], bhf[4];
        #pragma unroll
        for (int mi = 0; mi < 4; ++mi)
            af[mi] = *(const bf16x8*)&XhS[wm * 64 + mi * 16 + l16][quad * 8];
        #pragma unroll
        for (int ni = 0; ni < 4; ++ni)
            bhf[ni] = *(const bf16x8*)
                &YhS[wn * 64 + ni * 16 + l16][(quad * 8) ^ ((ni & 3) << 3)];
        #pragma unroll
        for (int mi = 0; mi < 4; ++mi)
            #pragma unroll
            for (int ni = 0; ni < 4; ++ni)
                acc[mi][ni] = MFMA(af[mi], bhf[ni], acc[mi][ni]);
    }
    // lane's 4 j's are contiguous: jb..jb+3
    const int jb = bn + wn * 64 + (l16 << 2);
    const float4 nyv = *(const float4*)(nb + jb);
    const float nyl[4] = {nyv.x, nyv.y, nyv.z, nyv.w};
    // --- transform in place + vector store ---
    #pragma unroll
    for (int mi = 0; mi < 4; ++mi)
        #pragma unroll
        for (int r = 0; r < 4; ++r) {
            int gm = bm + wm * 64 + mi * 16 + quad * 4 + r;
            float nxm = nx[gm];
            f16x4 ov;
            #pragma unroll
            for (int ni = 0; ni < 4; ++ni) {
                float d2 = nxm + nyl[ni] - 2.0f * acc[mi][ni][r];
                float a = -sqrtf(fmaxf(d2, 0.0f)) * INV_T;
                if (mat && gm == jb + ni) a = -5.0e6f;
                acc[mi][ni][r] = a;
                ov[ni] = (f16)a;
            }
            *(f16x4*)(Out + (size_t)gm * N + jb) = ov;
        }
    // --- row partials: per (mi,r), reduce over ni (in-lane) + l16 (shfl) ---
    const int ct = blockIdx.x * 2 + wn;
    #pragma unroll
    for (int mi = 0; mi < 4; ++mi)
        #pragma unroll
        for (int r = 0; r < 4; ++r) {
            float m = fmaxf(fmaxf(acc[mi][0][r], acc[mi][1][r]),
                            fmaxf(acc[mi][2][r], acc[mi][3][r]));
            m = fmaxf(m, __shfl_xor(m, 1));
            m = fmaxf(m, __shfl_xor(m, 2));
            m = fmaxf(m, __shfl_xor(m, 4));
            m = fmaxf(m, __shfl_xor(m, 8));
            float s = __expf(acc[mi][0][r] - m) + __expf(acc[mi][1][r] - m)
                    + __expf(acc[mi][2][r] - m) + __expf(acc[mi][3][r] - m);
            s += __shfl_xor(s, 1); s += __shfl_xor(s, 2);
            s += __shfl_xor(s, 4); s += __shfl_xor(s, 8);
            if (l16 == 0) {
                int grow = bm + wm * 64 + mi * 16 + quad * 4 + r;
                prm[(size_t)ct * N + grow] = m;
                prs[(size_t)ct * N + grow] = s;
            }
        }
    // --- col partials (pos only): per ni, in-lane over (mi,r) + quad shfl ---
    if (mat == 0) {
        const int rt = blockIdx.y * 2 + wm;
        #pragma unroll
        for (int ni = 0; ni < 4; ++ni) {
            float m = -3.0e38f;
            #pragma unroll
            for (int mi = 0; mi < 4; ++mi)
                #pragma unroll
                for (int r = 0; r < 4; ++r)
                    m = fmaxf(m, acc[mi][ni][r]);
            m = fmaxf(m, __shfl_xor(m, 16));
            m = fmaxf(m, __shfl_xor(m, 32));
            float s = 0.f;
            #pragma unroll
            for (int mi = 0; mi < 4; ++mi)
                #pragma unroll
                for (int r = 0; r < 4; ++r)
                    s += __expf(acc[mi][ni][r] - m);
            s += __shfl_xor(s, 16);
            s += __shfl_xor(s, 32);
            if (quad == 0) {
                pcm_p[(size_t)rt * N + jb + ni] = m;
                pcs_p[(size_t)rt * N + jb + ni] = s;
            }
        }
    }
}

// ---------------------------------------------------------------------------
// Combine partials into row/col softmax stats — parallel (192 x 256).
// ---------------------------------------------------------------------------
__global__ __launch_bounds__(256) void stats_combine(
    const float* __restrict__ prm_p, const float* __restrict__ prs_p,
    const float* __restrict__ prm_n, const float* __restrict__ prs_n,
    const float* __restrict__ pcm_p, const float* __restrict__ pcs_p,
    float* __restrict__ m_row, float* __restrict__ isr,
    float* __restrict__ m_col, float* __restrict__ isc)
{
    __shared__ float Ms[4][64], Ss[4][64];
    const int t = threadIdx.x;
    const int g = t >> 6, l = t & 63;
    const int idx = blockIdx.x * 64 + l;
    const int c0 = g * 16;

    float m = -3.0e38f, s = 0.f;
    if (idx < N) {
        const int i = idx;
        #pragma unroll 4
        for (int c = c0; c < c0 + 16; ++c) {
            m = fmaxf(m, prm_p[(size_t)c * N + i]);
            m = fmaxf(m, prm_n[(size_t)c * N + i]);
        }
        #pragma unroll 4
        for (int c = c0; c < c0 + 16; ++c) {
            s += prs_p[(size_t)c * N + i] * __expf(prm_p[(size_t)c * N + i] - m);
            s += prs_n[(size_t)c * N + i] * __expf(prm_n[(size_t)c * N + i] - m);
        }
    } else {
        const int mat = (idx - N) >> 12;
        const int j = idx & (N - 1);
        const float* pm = mat ? prm_n : pcm_p;
        const float* ps = mat ? prs_n : pcs_p;
        #pragma unroll 4
        for (int c = c0; c < c0 + 16; ++c)
            m = fmaxf(m, pm[(size_t)c * N + j]);
        #pragma unroll 4
        for (int c = c0; c < c0 + 16; ++c)
            s += ps[(size_t)c * N + j] * __expf(pm[(size_t)c * N + j] - m);
    }
    Ms[g][l] = m; Ss[g][l] = s;
    __syncthreads();
    if (g == 0) {
        float m0 = Ms[0][l], m1 = Ms[1][l], m2 = Ms[2][l], m3 = Ms[3][l];
        float mm = fmaxf(fmaxf(m0, m1), fmaxf(m2, m3));
        float ss = Ss[0][l] * __expf(m0 - mm) + Ss[1][l] * __expf(m1 - mm)
                 + Ss[2][l] * __expf(m2 - mm) + Ss[3][l] * __expf(m3 - mm);
        if (idx < N) {
            m_row[idx] = mm;
            isr[idx] = 1.0f / sqrtf(ss);
        } else {
            const int mat = (idx - N) >> 12;
            const int j = idx & (N - 1);
            m_col[mat * N + j] = mm;
            isc[mat * N + j] = 1.0f / sqrtf(ss);
        }
    }
}

// ---------------------------------------------------------------------------
// pv via MFMA (proven form): A fp16 tile -> P (fp32 rowsums -> sp/sn),
// split P (trunc) to bf16 hi/lo in LDS, MFMA P @ B (B = RTN-bf16 transposed
// [d][j], hi only). Unpermuted staging; scalar C-stores (lane-coalesced).
// ---------------------------------------------------------------------------
__global__ __launch_bounds__(256) void pv_mfma(
    const f16* __restrict__ Apos, const f16* __restrict__ Aneg,
    const u16* __restrict__ Yth, const u16* __restrict__ Xth,
    const float* __restrict__ m_row, const float* __restrict__ isr,
    const float* __restrict__ m_col, const float* __restrict__ isc,
    float* __restrict__ u_part, float* __restrict__ w_part,
    float* __restrict__ sp_arr, float* __restrict__ sn_arr)
{
    const int mat = blockIdx.z;
    const f16* Am = mat ? Aneg : Apos;
    const u16* Bh = mat ? Xth : Yth;
    const float* mc = m_col + mat * N;
    const float* ic = isc + mat * N;
    float* Cp = (mat ? w_part : u_part) + (size_t)blockIdx.y * (N * D);
    float* spn = mat ? sn_arr : sp_arr;

    __shared__ u16 BhS[128][72];
    __shared__ u16 PhS[64][72], PlS[64][72];
    __shared__ float mrS[64], isrS[64];

    const int t = threadIdx.x;
    const int w = t >> 6, lane = t & 63;
    const int quad = lane >> 4, l16 = lane & 15;
    const int bm = blockIdx.x * 64;
    const int jbase = blockIdx.y * (N / KSPLIT);
    const int arow = t >> 4;          // 0..15
    const int aj = (t & 15) << 2;     // 0..60

    if (t < 64) { mrS[t] = m_row[bm + t]; isrS[t] = isr[bm + t]; }

    f32x4 acc[8] = {};
    float rs[4] = {0.f, 0.f, 0.f, 0.f};

    for (int jt = 0; jt < (N / KSPLIT) / 64; ++jt) {
        const int j0 = jbase + jt * 64;
        __syncthreads();   // protect previous iteration's LDS reads (+ mrS init)
        #pragma unroll
        for (int p = 0; p < 4; ++p) {
            int slot = t + p * 256;
            int d = slot >> 3, joff = (slot & 7) << 3;
            *(u16x8*)&BhS[d][joff] = *(const u16x8*)(Bh + (size_t)d * N + j0 + joff);
        }
        float4 mcv = *(const float4*)(mc + j0 + aj);
        float4 icv = *(const float4*)(ic + j0 + aj);
        #pragma unroll
        for (int s = 0; s < 4; ++s) {
            int row = arow + s * 16;
            f16x4 av = *(const f16x4*)(Am + (size_t)(bm + row) * N + j0 + aj);
            float mr = mrS[row], sr = isrS[row];
            float p0 = __expf((float)av.x - 0.5f * (mr + mcv.x)) * (sr * icv.x);
            float p1 = __expf((float)av.y - 0.5f * (mr + mcv.y)) * (sr * icv.y);
            float p2 = __expf((float)av.z - 0.5f * (mr + mcv.z)) * (sr * icv.z);
            float p3 = __expf((float)av.w - 0.5f * (mr + mcv.w)) * (sr * icv.w);
            rs[s] += p0 + p1 + p2 + p3;
            ushort4 hv, lv;
            split1_trunc(p0, hv.x, lv.x); split1_trunc(p1, hv.y, lv.y);
            split1_trunc(p2, hv.z, lv.z); split1_trunc(p3, hv.w, lv.w);
            *(ushort4*)&PhS[row][aj] = hv;
            *(ushort4*)&PlS[row][aj] = lv;
        }
        __syncthreads();
        #pragma unroll
        for (int ks = 0; ks < 2; ++ks) {
            const int kk = ks * 32 + quad * 8;
            bf16x8 ph = *(const bf16x8*)&PhS[w * 16 + l16][kk];
            bf16x8 pl = *(const bf16x8*)&PlS[w * 16 + l16][kk];
            #pragma unroll
            for (int ni = 0; ni < 8; ++ni) {
                bf16x8 bh = *(const bf16x8*)&BhS[ni * 16 + l16][kk];
                acc[ni] = MFMA(ph, bh, acc[ni]);
                acc[ni] = MFMA(pl, bh, acc[ni]);
            }
        }
    }
    #pragma unroll
    for (int ni = 0; ni < 8; ++ni)
        #pragma unroll
        for (int r = 0; r < 4; ++r) {
            int row = w * 16 + quad * 4 + r;
            int col = ni * 16 + l16;
            Cp[(size_t)(bm + row) * D + col] = acc[ni][r];
        }
    #pragma unroll
    for (int s = 0; s < 4; ++s) {
        float v = rs[s];
        v += __shfl_xor(v, 1); v += __shfl_xor(v, 2);
        v += __shfl_xor(v, 4); v += __shfl_xor(v, 8);
        if (l16 == 0) atomicAdd(&spn[bm + arow + s * 16], v);
    }
}

// ---------------------------------------------------------------------------
// Sum split-K partials, V = sn*u - sp*sn*w, accumulate sum(V^2).
// ---------------------------------------------------------------------------
__global__ __launch_bounds__(256) void final_reduce(const float* __restrict__ u_part,
    const float* __restrict__ w_part, const float* __restrict__ sp_arr,
    const float* __restrict__ sn_arr, double* __restrict__ acc_out)
{
    __shared__ float red[256];
    const int t = threadIdx.x;
    const int idx = blockIdx.x * 256 + t;
    float u = 0.f, w = 0.f;
    #pragma unroll
    for (int c = 0; c < KSPLIT; ++c) {
        u += u_part[(size_t)c * (N * D) + idx];
        w += w_part[(size_t)c * (N * D) + idx];
    }
    const int i = idx >> 7;
    const float sn = sn_arr[i];
    const float v = sn * u - sp_arr[i] * sn * w;
    red[t] = v * v; __syncthreads();
    for (int s = 128; s > 0; s >>= 1) { if (t < s) red[t] += red[t + s]; __syncthreads(); }
    if (!t) atomicAdd(acc_out, (double)red[0]);
}

__global__ void finalize(const double* __restrict__ acc, float* __restrict__ out)
{
    out[0] = (float)(*acc * (1.0 / ((double)N * (double)D)));
}

// ---------------------------------------------------------------------------
extern "C" void kernel_launch(void* const* d_in, const int* in_sizes, int n_in,
                              void* d_out, int out_size, void* d_ws, size_t ws_size,
                              hipStream_t stream)
{
    const float* y_pos = (const float*)d_in[0];
    const float* eps   = (const float*)d_in[1];
    const float* W_in  = (const float*)d_in[2];
    const float* b_in  = (const float*)d_in[3];
    const float* W_blk = (const float*)d_in[4];
    const float* b_blk = (const float*)d_in[5];
    const float* W_out = (const float*)d_in[6];
    const float* b_out = (const float*)d_in[7];
    float* out = (float*)d_out;
    (void)in_sizes; (void)n_in; (void)out_size; (void)ws_size;

    char* p = (char*)d_ws;
    auto alloc = [&](size_t bytes) {
        char* r = p;
        p += (bytes + 255) & ~(size_t)255;
        return r;
    };
    // --- small arrays ---
    double* acc  = (double*)alloc(8);
    float* sp     = (float*)alloc(N * 4);
    float* sn     = (float*)alloc(N * 4);
    float* m_row  = (float*)alloc(N * 4);
    float* isr    = (float*)alloc(N * 4);
    float* m_col  = (float*)alloc(2 * N * 4);
    float* isc    = (float*)alloc(2 * N * 4);
    float* nx     = (float*)alloc(N * 4);
    float* ny     = (float*)alloc(N * 4);
    // --- eh/el (2 MB; only live through the first gen layer) ---
    u16* eh = (u16*)alloc((size_t)N * D * 2);
    u16* el = (u16*)alloc((size_t)N * D * 2);
    // --- xo fp32 + bf16 x/y arrays ---
    float* xo  = (float*)alloc((size_t)N * D * 4);
    u16* xh    = (u16*)alloc((size_t)N * D * 2);
    u16* xl    = (u16*)alloc((size_t)N * D * 2);
    u16* xth   = (u16*)alloc((size_t)N * D * 2);
    u16* yh    = (u16*)alloc((size_t)N * D * 2);
    u16* yl    = (u16*)alloc((size_t)N * D * 2);
    u16* yth   = (u16*)alloc((size_t)N * D * 2);
    // --- generator region (21 MB): activations + weights; later aliased by
    //     stats partials (6 MB) then u/w_part (16 MB) ---
    char* genreg = alloc((size_t)(4 * (size_t)N * H * 2
                                + 2 * (size_t)H * D * 2
                                + 2 * (size_t)4 * H * H * 2
                                + 2 * (size_t)D * H * 2));
    u16* x0h = (u16*)genreg;
    u16* x0l = x0h + (size_t)N * H;
    u16* x1h = x0l + (size_t)N * H;
    u16* x1l = x1h + (size_t)N * H;
    u16* wih = x1l + (size_t)N * H;
    u16* wil = wih + (size_t)H * D;
    u16* wbh = wil + (size_t)H * D;
    u16* wbl = wbh + (size_t)4 * H * H;
    u16* woh = wbl + (size_t)4 * H * H;
    u16* wol = woh + (size_t)D * H;
    // aliases (disjoint lifetimes, stream-ordered):
    float* prm_p = (float*)genreg;                 // 64*N each = 1 MB
    float* prs_p = prm_p + 64 * N;
    float* prm_n = prs_p + 64 * N;
    float* prs_n = prm_n + 64 * N;
    float* pcm_p = prs_n + 64 * N;
    float* pcs_p = pcm_p + 64 * N;                 // ends at 6 MB
    float* u_part = (float*)genreg;                // KSPLIT*N*D = 8 MB
    float* w_part = u_part + (size_t)KSPLIT * N * D;
    // --- the big ones (64 MB, fp16) ---
    f16* Apos = (f16*)alloc((size_t)N * N * 2);
    f16* Aneg = (f16*)alloc((size_t)N * N * 2);

    // --- split inputs/weights to bf16 hi/lo (RTN) + workspace init (y==5) ---
    SplitArgs sa;
    sa.d[0] = { eps,   eh,  el,  N * D };
    sa.d[1] = { y_pos, yh,  yl,  N * D };
    sa.d[2] = { W_in,  wih, wil, H * D };
    sa.d[3] = { W_blk, wbh, wbl, 4 * H * H };
    sa.d[4] = { W_out, woh, wol, D * H };
    split_multi<<<dim3(1024, 6), 256, 0, stream>>>(sa, acc, sp, sn, nx, ny);

    // --- generator (MFMA, act hi/lo x W-RTN, 64x64 blocks, BK=128) ---
    dim3 gh(H / 64, N / 64);
    gen_gemm<<<gh, 128, 0, stream>>>(eh, el, wih, b_in,
                                     nullptr, x0h, x0l, N, H, D, 0, 0);
    gen_gemm<<<gh, 128, 0, stream>>>(x0h, x0l, wbh + 0 * H * H,
                                     b_blk + 0 * H, nullptr, x1h, x1l, N, H, H, 1, 0);
    gen_gemm<<<gh, 128, 0, stream>>>(x1h, x1l, wbh + 1 * H * H,
                                     b_blk + 1 * H, nullptr, x0h, x0l, N, H, H, 1, 0);
    gen_gemm<<<gh, 128, 0, stream>>>(x0h, x0l, wbh + 2 * H * H,
                                     b_blk + 2 * H, nullptr, x1h, x1l, N, H, H, 1, 0);
    gen_gemm<<<gh, 128, 0, stream>>>(x1h, x1l, wbh + 3 * H * H,
                                     b_blk + 3 * H, nullptr, x0h, x0l, N, H, H, 1, 0);
    gen_gemm<<<dim3(D / 64, N / 64), 128, 0, stream>>>(x0h, x0l, woh, b_out,
                                     xo, xh, xl, N, D, H, 0, 1);

    // --- RTN transposes + fused row norms ---
    transpose_rtn<<<dim3(N / 32, D / 32, 2), 256, 0, stream>>>(
        xo, y_pos, xth, yth, nx, ny);

    // --- distance matrices (fp16, single-bf16 MFMA) + fused stats ---
    dist_fused<<<dim3(N / 128, N / 128, 2), 256, 0, stream>>>(
        xh, yh, nx, ny, Apos, Aneg,
        prm_p, prs_p, pcm_p, pcs_p, prm_n, prs_n);

    // --- combine partials into m_row/isr, m_col/isc (parallel) ---
    stats_combine<<<192, 256, 0, stream>>>(prm_p, prs_p, prm_n, prs_n,
                                           pcm_p, pcs_p,
                                           m_row, isr, m_col, isc);

    // --- P@V via MFMA (P built on the fly; sp/sn fp32 via atomics) ---
    pv_mfma<<<dim3(N / 64, KSPLIT, 2), 256, 0, stream>>>(Apos, Aneg,
        yth, xth, m_row, isr, m_col, isc, u_part, w_part, sp, sn);

    // --- combine partials, V^2 reduction ---
    final_reduce<<<(N * D) / 256, 256, 0, stream>>>(u_part, w_part, sp, sn, acc);
    finalize<<<1, 1, 0, stream>>>(acc, out);
}